// Round 2
// baseline (11611.528 us; speedup 1.0000x reference)
//
#include <hip/hip_runtime.h>
#include <hip/hip_bf16.h>
#include <math.h>

typedef unsigned short u16;
typedef short s16x8 __attribute__((ext_vector_type(8)));
typedef float f32x4v __attribute__((ext_vector_type(4)));

#define EDIM 300
#define EPAD 320

// ---- fixed workspace layout (bytes) ----
static constexpr size_t SZ_WIH  = (size_t)2 * 1024 * EPAD * 2;   // bf16 [2][1024][320]
static constexpr size_t SZ_WHH  = (size_t)2 * 1024 * 256 * 2;    // bf16 [2][1024][256]
static constexpr size_t SZ_BIAS = (size_t)2 * 1024 * 4;          // f32  [2][1024]
static constexpr size_t SZ_HG   = (size_t)2 * 4 * 128 * 256 * 2; // bf16 [2 parity][4 runs][128][256]
static constexpr size_t SZ_CNT  = 256;                           // u32[64]
static constexpr size_t SZ_CST  = (size_t)4 * 128 * 256 * 4;     // f32 c-state
static constexpr size_t SZ_VAC  = (size_t)4 * 128 * 256 * 4;     // f32 vacc-state
static constexpr size_t SZ_VOUT = (size_t)2 * 128 * 512 * 4;     // f32 [2][128][512]
static constexpr size_t FIXED_B = SZ_WIH + SZ_WHH + SZ_BIAS + SZ_HG + SZ_CNT + SZ_CST + SZ_VAC + SZ_VOUT;
// per-timestep chunk cost: e_chunk [512][T][320]bf16 + gin_chunk [512][T][1024]bf16
static constexpr size_t PER_T   = (size_t)512 * EPAD * 2 + (size_t)512 * 1024 * 2;  // 1,376,256

__device__ __forceinline__ float bf2f(u16 u) {
  union { float f; unsigned int i; } v; v.i = ((unsigned int)u) << 16; return v.f;
}
__device__ __forceinline__ u16 f2bf(float f) {
  union { float f; unsigned int i; } v; v.f = f;
  unsigned int r = v.i + 0x7fffu + ((v.i >> 16) & 1u);   // RNE (finite inputs)
  return (u16)(r >> 16);
}
__device__ __forceinline__ void gload_lds16(const void* g, void* l) {
  __builtin_amdgcn_global_load_lds((const __attribute__((address_space(1))) void*)g,
                                   (__attribute__((address_space(3))) void*)l, 16, 0, 0);
}

// ---------------- prep: weights -> bf16, bias sum, counter zero ----------------
__global__ void prep_kernel(const float* wih_f, const float* whh_f, const float* bih_f, const float* bhh_f,
                            const float* wih_b, const float* whh_b, const float* bih_b, const float* bhh_b,
                            u16* wih_bf, u16* whh_bf, float* bias, unsigned int* cnt)
{
  int tid = blockIdx.x * blockDim.x + threadIdx.x;
  if (tid < 2 * 1024 * EPAD) {
    int d = tid / (1024 * EPAD); int rr = tid % (1024 * EPAD);
    int j = rr / EPAD; int k = rr % EPAD;
    const float* w = d ? wih_b : wih_f;
    wih_bf[tid] = (k < EDIM) ? f2bf(w[(size_t)j * EDIM + k]) : (u16)0;
  }
  int t1 = tid - 2 * 1024 * EPAD;
  if (t1 >= 0 && t1 < 2 * 1024 * 256) {
    int d = t1 / (1024 * 256); int rr = t1 % (1024 * 256);
    const float* w = d ? whh_b : whh_f;
    whh_bf[t1] = f2bf(w[rr]);
  }
  int t2 = t1 - 2 * 1024 * 256;
  if (t2 >= 0 && t2 < 2 * 1024) {
    int d = t2 >> 10; int j = t2 & 1023;
    bias[t2] = d ? (bih_b[j] + bhh_b[j]) : (bih_f[j] + bhh_f[j]);
  }
  int t3 = t2 - 2 * 1024;
  if (t3 >= 0 && t3 < 64) cnt[t3] = 0u;
}

// ---------------- embedding gather for one time-chunk ----------------
// row = ((dir*2+seq)*128 + b)*T + tl ; token consumed at global step t0+tl
__global__ void embed_chunk_kernel(const int* x1, const int* x2, const float* emb,
                                   u16* ec, int t0, int T)
{
  int row = blockIdx.x;
  int k = threadIdx.x;            // 0..319
  int tl = row % T;
  int rb = row / T;               // (dir*2+seq)*128 + b
  int b = rb & 127;
  int ds = rb >> 7;
  int dir = ds >> 1, seq = ds & 1;
  const int* x = seq ? x2 : x1;
  int t = t0 + tl;
  int tok = x[b * 256 + (dir ? (255 - t) : t)];
  float v = (k < EDIM) ? emb[(size_t)tok * EDIM + k] : 0.0f;
  ec[(size_t)row * EPAD + k] = f2bf(v);
}

// ---------------- input projection GEMM for one chunk ----------------
// C[row][j] = ec[row] . Wih_dir(row)[j];  M = 512*T, N = 1024/dir, K = 320
__global__ void __launch_bounds__(256, 2)
gemm_chunk_kernel(const u16* __restrict__ ec, const u16* __restrict__ wih_bf,
                  u16* __restrict__ ginc, int T)
{
  __shared__ __align__(16) u16 As[128 * 64];
  __shared__ __align__(16) u16 Bs[128 * 64];
  int m0 = blockIdx.x * 128;
  int d  = (m0 >= 256 * T) ? 1 : 0;      // dir-major row layout; tiles never straddle
  int n0 = blockIdx.y * 128;
  int lane = threadIdx.x & 63;
  int w = threadIdx.x >> 6;
  int wm = w >> 1, wn = w & 1;

  f32x4v acc[4][4] = {};
  const char* Abase = (const char*)ec;                                  // [512T][320] bf16
  const char* Bbase = (const char*)(wih_bf + (size_t)d * 1024 * EPAD);  // [1024][320] bf16

  int ar  = lane >> 3;            // row within 8-row stripe
  int acb = (lane & 7) * 16;      // byte col (16B slot)
  int sw  = ar << 4;

  for (int kt = 0; kt < 5; ++kt) {
    int k0b = kt * 128;
    #pragma unroll
    for (int i = 0; i < 4; ++i) {
      int lrow = (i * 4 + w) * 8 + ar;
      gload_lds16(Abase + (size_t)(m0 + lrow) * 640 + k0b + (acb ^ sw),
                  (char*)As + (i * 4 + w) * 1024);
      gload_lds16(Bbase + (size_t)(n0 + lrow) * 640 + k0b + (acb ^ sw),
                  (char*)Bs + (i * 4 + w) * 1024);
    }
    __syncthreads();
    #pragma unroll
    for (int kc = 0; kc < 2; ++kc) {
      s16x8 a[4], b[4];
      int cb = kc * 64 + (lane >> 4) * 16;
      #pragma unroll
      for (int mf = 0; mf < 4; ++mf) {
        int rr = wm * 64 + mf * 16 + (lane & 15);
        a[mf] = *(const s16x8*)((const char*)As + rr * 128 + (cb ^ ((rr & 7) << 4)));
      }
      #pragma unroll
      for (int nf = 0; nf < 4; ++nf) {
        int rr = wn * 64 + nf * 16 + (lane & 15);
        b[nf] = *(const s16x8*)((const char*)Bs + rr * 128 + (cb ^ ((rr & 7) << 4)));
      }
      #pragma unroll
      for (int mf = 0; mf < 4; ++mf)
        #pragma unroll
        for (int nf = 0; nf < 4; ++nf)
          acc[mf][nf] = __builtin_amdgcn_mfma_f32_16x16x32_bf16(a[mf], b[nf], acc[mf][nf], 0, 0, 0);
    }
    __syncthreads();
  }

  #pragma unroll
  for (int mf = 0; mf < 4; ++mf)
    #pragma unroll
    for (int nf = 0; nf < 4; ++nf) {
      int col = n0 + wn * 64 + nf * 16 + (lane & 15);
      #pragma unroll
      for (int i = 0; i < 4; ++i) {
        int row = m0 + wm * 64 + mf * 16 + (lane >> 4) * 4 + i;
        ginc[(size_t)row * 1024 + col] = f2bf(acc[mf][nf][i]);
      }
    }
}

// ---------------- recurrent bi-LSTM for one time-chunk (plain launch) ----------------
// 256 blocks: r(4 runs) x bt(16 batch-tiles of 8) x kq(4 hidden-quarters of 64).
// Co-residency guaranteed by capacity (<=256 VGPR, 26KB LDS -> >=2 blocks/CU machine-wide).
__global__ void __launch_bounds__(256, 2)
lstm_chunk_kernel(const u16* __restrict__ ginc, const u16* __restrict__ whh_bf,
                  const float* __restrict__ bias, u16* hg, unsigned int* cnt,
                  float* cstate, float* vaccst, float* vout,
                  const int* len1, const int* len2, int t0, int T)
{
  __shared__ __align__(16) u16 h_lds[16 * 264];   // [16 rows(8 real)][256 k] + 8 pad
  __shared__ float g_lds[16 * 258];
  __shared__ float bias_lds[256];

  const int bid = blockIdx.x;
  const int r  = bid >> 6;
  const int bt = (bid >> 2) & 15;
  const int kq = bid & 3;
  const int dir = r & 1, seq = r >> 1;
  const int tid = threadIdx.x;
  const int lane = tid & 63, w = tid >> 6;        // wave w = gate (i,f,g,o)
  const int kp = lane, b0 = w;
  const int blk_b = bt * 8;
  const int* len = seq ? len2 : len1;
  const u16* whh = whh_bf + (size_t)dir * 1024 * 256;
  unsigned int* mycnt = cnt + (r * 16 + bt);

  // Whh B-fragments in registers: wave w covers j = w*256 + kq*64 + [0,64)
  s16x8 bfr[4][8];
  #pragma unroll
  for (int nf = 0; nf < 4; ++nf)
    #pragma unroll
    for (int kc = 0; kc < 8; ++kc) {
      int j = w * 256 + kq * 64 + nf * 16 + (lane & 15);
      int k = kc * 32 + (lane >> 4) * 8;
      bfr[nf][kc] = *(const s16x8*)(whh + (size_t)j * 256 + k);
    }

  bias_lds[tid] = bias[(size_t)dir * 1024 + w * 256 + kq * 64 + lane];
  for (int i = tid; i < 16 * 264; i += 256) h_lds[i] = 0;
  __syncthreads();
  if (t0 > 0) {   // resume h from previous chunk
    int bb = tid >> 5, cc = (tid & 31) * 8;
    const u16* src = hg + ((size_t)(t0 & 1) * 4 + r) * 32768 + (size_t)(blk_b + bb) * 256 + cc;
    *(s16x8*)&h_lds[bb * 264 + cc] = *(const s16x8*)src;
  }
  __syncthreads();

  float c[2] = {0.f, 0.f}, vacc[2] = {0.f, 0.f};
  int lenm1[2] = { len[blk_b + b0] - 1, len[blk_b + b0 + 4] - 1 };
  if (t0 > 0) {
    #pragma unroll
    for (int pp = 0; pp < 2; ++pp) {
      size_t idx = ((size_t)r * 128 + blk_b + b0 + pp * 4) * 256 + kq * 64 + kp;
      c[pp] = cstate[idx];
      vacc[pp] = vaccst[idx];
    }
  }

  size_t gb[2];
  #pragma unroll
  for (int pp = 0; pp < 2; ++pp)
    gb[pp] = ((size_t)((dir * 2 + seq) * 128 + blk_b + b0 + pp * 4) * (size_t)T) * 1024 + kq * 64 + kp;
  u16 gv[2][4];
  #pragma unroll
  for (int pp = 0; pp < 2; ++pp) {   // prefetch step t0
    gv[pp][0] = ginc[gb[pp]];       gv[pp][1] = ginc[gb[pp] + 256];
    gv[pp][2] = ginc[gb[pp] + 512]; gv[pp][3] = ginc[gb[pp] + 768];
  }

  for (int t = t0; t < t0 + T; ++t) {
    // S = h(t) @ Whh^T (this block's 256-j chunk)
    s16x8 a[8];
    #pragma unroll
    for (int kc = 0; kc < 8; ++kc)
      a[kc] = *(const s16x8*)&h_lds[(lane & 15) * 264 + kc * 32 + (lane >> 4) * 8];
    #pragma unroll
    for (int nf = 0; nf < 4; ++nf) {
      f32x4v acc = {0.f, 0.f, 0.f, 0.f};
      #pragma unroll
      for (int kc = 0; kc < 8; ++kc)
        acc = __builtin_amdgcn_mfma_f32_16x16x32_bf16(a[kc], bfr[nf][kc], acc, 0, 0, 0);
      #pragma unroll
      for (int i = 0; i < 4; ++i)
        g_lds[((lane >> 4) * 4 + i) * 258 + w * 64 + nf * 16 + (lane & 15)] = acc[i];
    }
    __syncthreads();

    // consume prefetched Gin, then issue prefetch for next step
    float gx[2][4];
    #pragma unroll
    for (int pp = 0; pp < 2; ++pp)
      #pragma unroll
      for (int g = 0; g < 4; ++g) gx[pp][g] = bf2f(gv[pp][g]);
    int tln = t + 1 - t0; if (tln >= T) tln = T - 1;
    #pragma unroll
    for (int pp = 0; pp < 2; ++pp) {
      size_t a0 = gb[pp] + (size_t)tln * 1024;
      gv[pp][0] = ginc[a0];       gv[pp][1] = ginc[a0 + 256];
      gv[pp][2] = ginc[a0 + 512]; gv[pp][3] = ginc[a0 + 768];
    }

    int tmap = dir ? (255 - t) : t;
    int p1 = (t + 1) & 1;
    #pragma unroll
    for (int pp = 0; pp < 2; ++pp) {
      int b = b0 + pp * 4;
      float si = g_lds[b * 258 +   0 + kp] + gx[pp][0] + bias_lds[  0 + kp];
      float sf = g_lds[b * 258 +  64 + kp] + gx[pp][1] + bias_lds[ 64 + kp];
      float sg = g_lds[b * 258 + 128 + kp] + gx[pp][2] + bias_lds[128 + kp];
      float so = g_lds[b * 258 + 192 + kp] + gx[pp][3] + bias_lds[192 + kp];
      float I = 1.f / (1.f + __expf(-si));
      float F = 1.f / (1.f + __expf(-sf));
      float sgc = fminf(fmaxf(sg, -15.f), 15.f);
      float e2 = __expf(2.f * sgc);
      float G = (e2 - 1.f) / (e2 + 1.f);
      float O = 1.f / (1.f + __expf(-so));
      float cn = F * c[pp] + I * G;
      c[pp] = cn;
      float cc2 = fminf(fmaxf(cn, -15.f), 15.f);
      float ec2 = __expf(2.f * cc2);
      float hn = O * (ec2 - 1.f) / (ec2 + 1.f);
      if (tmap < lenm1[pp]) vacc[pp] += hn;
      hg[((size_t)p1 * 4 + r) * 32768 + (size_t)(blk_b + b) * 256 + kq * 64 + kp] = f2bf(hn);
    }
    __threadfence();
    __syncthreads();
    if (tid == 0) {
      __hip_atomic_fetch_add(mycnt, 1u, __ATOMIC_RELEASE, __HIP_MEMORY_SCOPE_AGENT);
      unsigned int target = 4u * (unsigned)(t + 1);
      while (__hip_atomic_load(mycnt, __ATOMIC_ACQUIRE, __HIP_MEMORY_SCOPE_AGENT) < target)
        __builtin_amdgcn_s_sleep(1);
    }
    __syncthreads();
    __threadfence();
    {  // reload full h(t+1) rows for this batch tile
      int bb = tid >> 5, cc = (tid & 31) * 8;
      const u16* src = hg + ((size_t)p1 * 4 + r) * 32768 + (size_t)(blk_b + bb) * 256 + cc;
      *(s16x8*)&h_lds[bb * 264 + cc] = *(const s16x8*)src;
    }
    __syncthreads();
  }

  #pragma unroll
  for (int pp = 0; pp < 2; ++pp) {
    size_t idx = ((size_t)r * 128 + blk_b + b0 + pp * 4) * 256 + kq * 64 + kp;
    cstate[idx] = c[pp];
    vaccst[idx] = vacc[pp];
    if (t0 + T == 256) {
      int b = blk_b + b0 + pp * 4;
      vout[((size_t)seq * 128 + b) * 512 + dir * 256 + kq * 64 + kp] = vacc[pp] / (float)lenm1[pp];
    }
  }
}

// ---------------- MLP head ----------------
__global__ void mlp_kernel(const float* v, const float* W1, const float* b1,
                           const float* W2, const float* b2, const float* Wo, const float* bo,
                           float* out)
{
  __shared__ float vec[512];
  __shared__ float a1[512];
  __shared__ float red[4];
  int b = blockIdx.x;
  int tid = threadIdx.x;   // 256
  for (int i = tid; i < 512; i += 256)
    vec[i] = fabsf(v[(size_t)b * 512 + i] - v[(size_t)(128 + b) * 512 + i]);
  __syncthreads();
  for (int j = tid; j < 512; j += 256) {
    float s = b1[j];
    const float* wr = W1 + (size_t)j * 512;
    for (int k = 0; k < 512; ++k) s += vec[k] * wr[k];
    a1[j] = fmaxf(s, 0.f);
  }
  __syncthreads();
  float s = b2[tid];
  {
    const float* wr = W2 + (size_t)tid * 512;
    for (int k = 0; k < 512; ++k) s += a1[k] * wr[k];
  }
  float p = fmaxf(s, 0.f) * Wo[tid];
  for (int off = 32; off > 0; off >>= 1) p += __shfl_down(p, off);
  if ((tid & 63) == 0) red[tid >> 6] = p;
  __syncthreads();
  if (tid == 0) {
    float logit = red[0] + red[1] + red[2] + red[3] + bo[0];
    out[b] = logit;
    out[128 + b] = 1.f / (1.f + __expf(-logit));
  }
}

extern "C" void kernel_launch(void* const* d_in, const int* in_sizes, int n_in,
                              void* d_out, int out_size, void* d_ws, size_t ws_size,
                              hipStream_t stream)
{
  const int*   x1    = (const int*)d_in[0];
  const int*   x2    = (const int*)d_in[1];
  const int*   len1  = (const int*)d_in[2];
  const int*   len2  = (const int*)d_in[3];
  const float* emb   = (const float*)d_in[4];
  const float* wih_f = (const float*)d_in[5];
  const float* whh_f = (const float*)d_in[6];
  const float* bih_f = (const float*)d_in[7];
  const float* bhh_f = (const float*)d_in[8];
  const float* wih_b = (const float*)d_in[9];
  const float* whh_b = (const float*)d_in[10];
  const float* bih_b = (const float*)d_in[11];
  const float* bhh_b = (const float*)d_in[12];
  const float* W1    = (const float*)d_in[13];
  const float* b1    = (const float*)d_in[14];
  const float* W2    = (const float*)d_in[15];
  const float* b2    = (const float*)d_in[16];
  const float* Wo    = (const float*)d_in[17];
  const float* bo    = (const float*)d_in[18];

  char* p = (char*)d_ws;
  u16*   wih_bf = (u16*)p;          p += SZ_WIH;
  u16*   whh_bf = (u16*)p;          p += SZ_WHH;
  float* bias   = (float*)p;        p += SZ_BIAS;
  u16*   hg     = (u16*)p;          p += SZ_HG;
  unsigned int* cntp = (unsigned int*)p; p += SZ_CNT;
  float* cst    = (float*)p;        p += SZ_CST;
  float* vac    = (float*)p;        p += SZ_VAC;
  float* vout   = (float*)p;        p += SZ_VOUT;

  // adaptive time-chunk: largest power-of-two T with FIXED + T*PER_T <= ws_size
  int T = 256;
  while (T > 1 && FIXED_B + (size_t)T * PER_T > ws_size) T >>= 1;
  u16* ec   = (u16*)p;              p += (size_t)512 * T * EPAD * 2;
  u16* ginc = (u16*)p;

  {
    int total = 2 * 1024 * EPAD + 2 * 1024 * 256 + 2 * 1024 + 64;
    prep_kernel<<<(total + 255) / 256, 256, 0, stream>>>(
        wih_f, whh_f, bih_f, bhh_f, wih_b, whh_b, bih_b, bhh_b,
        wih_bf, whh_bf, bias, cntp);
  }

  int nch = 256 / T;
  for (int ch = 0; ch < nch; ++ch) {
    int tt0 = ch * T;
    embed_chunk_kernel<<<512 * T, EPAD, 0, stream>>>(x1, x2, emb, ec, tt0, T);
    gemm_chunk_kernel<<<dim3(4 * T, 8), 256, 0, stream>>>(ec, wih_bf, ginc, T);
    lstm_chunk_kernel<<<256, 256, 0, stream>>>(ginc, whh_bf, bias, hg, cntp,
                                               cst, vac, vout, len1, len2, tt0, T);
  }

  mlp_kernel<<<128, 256, 0, stream>>>(vout, W1, b1, W2, b2, Wo, bo, (float*)d_out);
}

// Round 3
// 2333.797 us; speedup vs baseline: 4.9754x; 4.9754x over previous
//
#include <hip/hip_runtime.h>
#include <hip/hip_bf16.h>
#include <math.h>

typedef unsigned short u16;
typedef short s16x8 __attribute__((ext_vector_type(8)));
typedef float f32x4v __attribute__((ext_vector_type(4)));

#define EDIM 300
#define EPAD 320

// ---- fixed workspace layout (bytes) ----
static constexpr size_t SZ_WIH  = (size_t)2 * 1024 * EPAD * 2;   // bf16 [2][1024][320]
static constexpr size_t SZ_WPK  = (size_t)2 * 16 * 8 * 4 * 64 * 8 * 2; // bf16 packed Whh frags (1 MB)
static constexpr size_t SZ_BIAS = (size_t)2 * 1024 * 4;          // f32  [2][1024]
static constexpr size_t SZ_HSV  = (size_t)2 * 256 * 256 * 2;     // bf16 h chunk-boundary save
static constexpr size_t SZ_CST  = (size_t)2 * 256 * 256 * 4;     // f32 c-state
static constexpr size_t SZ_VAC  = (size_t)2 * 256 * 256 * 4;     // f32 vacc-state
static constexpr size_t SZ_VOUT = (size_t)2 * 128 * 512 * 4;     // f32 [2][128][512]
static constexpr size_t FIXED_B = SZ_WIH + SZ_WPK + SZ_BIAS + SZ_HSV + SZ_CST + SZ_VAC + SZ_VOUT;
// per-timestep chunk cost: ec [512][T][320]bf16-equivalent rows + ginc rows
static constexpr size_t PER_T   = (size_t)512 * EPAD * 2 + (size_t)512 * 1024 * 2;  // 1,376,256

__device__ __forceinline__ float bf2f(u16 u) {
  union { float f; unsigned int i; } v; v.i = ((unsigned int)u) << 16; return v.f;
}
__device__ __forceinline__ u16 f2bf(float f) {
  union { float f; unsigned int i; } v; v.f = f;
  unsigned int r = v.i + 0x7fffu + ((v.i >> 16) & 1u);   // RNE (finite inputs)
  return (u16)(r >> 16);
}
__device__ __forceinline__ void gload_lds16(const void* g, void* l) {
  __builtin_amdgcn_global_load_lds((const __attribute__((address_space(1))) void*)g,
                                   (__attribute__((address_space(3))) void*)l, 16, 0, 0);
}

// ---------------- prep: Wih->bf16 padded, Whh->packed MFMA frags, bias sum ----------------
__global__ void prep_kernel(const float* wih_f, const float* whh_f, const float* bih_f, const float* bhh_f,
                            const float* wih_b, const float* whh_b, const float* bih_b, const float* bhh_b,
                            u16* wih_bf, u16* whh_pk, float* bias)
{
  int tid = blockIdx.x * blockDim.x + threadIdx.x;
  if (tid < 2 * 1024 * EPAD) {                      // Wih -> bf16, K padded 300->320
    int d = tid / (1024 * EPAD); int rr = tid % (1024 * EPAD);
    int j = rr / EPAD; int k = rr % EPAD;
    const float* w = d ? wih_b : wih_f;
    wih_bf[tid] = (k < EDIM) ? f2bf(w[(size_t)j * EDIM + k]) : (u16)0;
  }
  int t1 = tid - 2 * 1024 * EPAD;
  if (t1 >= 0 && t1 < 65536) {                      // Whh -> packed frags, 8 elems/thread
    int lane = t1 & 63;
    int nf = (t1 >> 6) & 3;
    int kc = (t1 >> 8) & 7;
    int w  = (t1 >> 11) & 15;
    int d  = (t1 >> 15) & 1;
    const float* src = d ? whh_b : whh_f;
    int j = w * 64 + nf * 16 + (lane & 15);
    int k = kc * 32 + (lane >> 4) * 8;
    u16* dst = whh_pk + (size_t)t1 * 8;
    #pragma unroll
    for (int kk = 0; kk < 8; ++kk)
      dst[kk] = f2bf(src[(size_t)j * 256 + k + kk]);
  }
  int t2 = t1 - 65536;
  if (t2 >= 0 && t2 < 2 * 1024) {                   // bias = bih + bhh
    int d = t2 >> 10; int j = t2 & 1023;
    bias[t2] = d ? (bih_b[j] + bhh_b[j]) : (bih_f[j] + bhh_f[j]);
  }
}

// ---------------- embedding gather for one time-chunk ----------------
// M-row = (d*T + tl)*256 + R, R = seq*128 + b
__global__ void embed_chunk_kernel(const int* x1, const int* x2, const float* emb,
                                   u16* ec, int t0, int T, int logT)
{
  int row = blockIdx.x;
  int k = threadIdx.x;            // 0..319
  int R  = row & 255;
  int tl = (row >> 8) & (T - 1);
  int d  = row >> (8 + logT);
  int seq = R >> 7, b = R & 127;
  const int* x = seq ? x2 : x1;
  int t = t0 + tl;
  int tok = x[b * 256 + (d ? (255 - t) : t)];
  float v = (k < EDIM) ? emb[(size_t)tok * EDIM + k] : 0.0f;
  ec[(size_t)row * EPAD + k] = f2bf(v);
}

// ---------------- input projection GEMM for one chunk ----------------
__global__ void __launch_bounds__(256, 2)
gemm_chunk_kernel(const u16* __restrict__ ec, const u16* __restrict__ wih_bf,
                  u16* __restrict__ ginc, int T, int logT)
{
  __shared__ __align__(16) u16 As[128 * 64];
  __shared__ __align__(16) u16 Bs[128 * 64];
  int m0 = blockIdx.x * 128;
  int d  = m0 >> (8 + logT);
  int n0 = blockIdx.y * 128;
  int lane = threadIdx.x & 63;
  int w = threadIdx.x >> 6;
  int wm = w >> 1, wn = w & 1;

  f32x4v acc[4][4] = {};
  const char* Abase = (const char*)ec;
  const char* Bbase = (const char*)(wih_bf + (size_t)d * 1024 * EPAD);

  int ar  = lane >> 3;
  int acb = (lane & 7) * 16;
  int sw  = ar << 4;

  for (int kt = 0; kt < 5; ++kt) {
    int k0b = kt * 128;
    #pragma unroll
    for (int i = 0; i < 4; ++i) {
      int lrow = (i * 4 + w) * 8 + ar;
      gload_lds16(Abase + (size_t)(m0 + lrow) * 640 + k0b + (acb ^ sw),
                  (char*)As + (i * 4 + w) * 1024);
      gload_lds16(Bbase + (size_t)(n0 + lrow) * 640 + k0b + (acb ^ sw),
                  (char*)Bs + (i * 4 + w) * 1024);
    }
    __syncthreads();
    #pragma unroll
    for (int kc = 0; kc < 2; ++kc) {
      s16x8 a[4], b[4];
      int cb = kc * 64 + (lane >> 4) * 16;
      #pragma unroll
      for (int mf = 0; mf < 4; ++mf) {
        int rr = wm * 64 + mf * 16 + (lane & 15);
        a[mf] = *(const s16x8*)((const char*)As + rr * 128 + (cb ^ ((rr & 7) << 4)));
      }
      #pragma unroll
      for (int nf = 0; nf < 4; ++nf) {
        int rr = wn * 64 + nf * 16 + (lane & 15);
        b[nf] = *(const s16x8*)((const char*)Bs + rr * 128 + (cb ^ ((rr & 7) << 4)));
      }
      #pragma unroll
      for (int mf = 0; mf < 4; ++mf)
        #pragma unroll
        for (int nf = 0; nf < 4; ++nf)
          acc[mf][nf] = __builtin_amdgcn_mfma_f32_16x16x32_bf16(a[mf], b[nf], acc[mf][nf], 0, 0, 0);
    }
    __syncthreads();
  }

  // epilogue: scatter to LSTM-friendly layout [d][bt32][tl][8 brow][1024 j]
  #pragma unroll
  for (int mf = 0; mf < 4; ++mf)
    #pragma unroll
    for (int nf = 0; nf < 4; ++nf) {
      int col = n0 + wn * 64 + nf * 16 + (lane & 15);
      #pragma unroll
      for (int i = 0; i < 4; ++i) {
        int row = m0 + wm * 64 + mf * 16 + (lane >> 4) * 4 + i;
        int R  = row & 255;
        int tl = (row >> 8) & (T - 1);
        int dd = row >> (8 + logT);
        size_t addr = ((((size_t)(dd * 32 + (R >> 3))) * T + tl) * 8 + (R & 7)) * 1024 + col;
        ginc[addr] = f2bf(acc[mf][nf][i]);
      }
    }
}

// ---------------- recurrent bi-LSTM: block-local recurrence, no inter-block sync ----------------
// 64 blocks: (dir d) x (bt in [0,32), 8 rows of the 256 (seq,b) rows). 16 waves/block.
// Wave w computes j in [w*64,(w+1)*64); Whh frags streamed from L2 (packed layout).
__global__ void __launch_bounds__(1024)
lstm_chunk_kernel(const u16* __restrict__ ginc, const u16* __restrict__ whh_pk,
                  const float* __restrict__ bias, u16* hsave,
                  float* cstate, float* vaccst, float* vout,
                  const int* len1, const int* len2, int t0, int T)
{
  __shared__ __align__(16) u16 h_lds[16 * 264];   // rows 0-7 real, 8-15 zero
  __shared__ float g_lds[8 * 1028];               // [8 brow][1024 j], stride 1028

  const int bid = blockIdx.x;
  const int d = bid >> 5, bt = bid & 31;
  const int tid = threadIdx.x;
  const int lane = tid & 63, w = tid >> 6;        // wave 0..15

  for (int i = tid; i < 16 * 264; i += 1024) h_lds[i] = 0;
  __syncthreads();

  const int brow0 = tid >> 8;                     // 0..3 (pairs brow0, brow0+4)
  const int u = tid & 255;

  if (t0 > 0) {
    #pragma unroll
    for (int pp = 0; pp < 2; ++pp) {
      int br = brow0 + pp * 4;
      h_lds[br * 264 + u] = hsave[((size_t)d * 256 + bt * 8 + br) * 256 + u];
    }
  }

  int lm[2];
  float bs[4], c[2] = {0.f, 0.f}, va[2] = {0.f, 0.f};
  #pragma unroll
  for (int pp = 0; pp < 2; ++pp) {
    int R = bt * 8 + brow0 + pp * 4;
    lm[pp] = ((R >> 7) ? len2 : len1)[R & 127] - 1;
  }
  #pragma unroll
  for (int g = 0; g < 4; ++g) bs[g] = bias[d * 1024 + g * 256 + u];
  if (t0 > 0) {
    #pragma unroll
    for (int pp = 0; pp < 2; ++pp) {
      size_t idx = ((size_t)d * 256 + bt * 8 + brow0 + pp * 4) * 256 + u;
      c[pp] = cstate[idx];
      va[pp] = vaccst[idx];
    }
  }

  const u16* wpk = whh_pk + (size_t)(d * 16 + w) * 16384;   // [kc][nf][lane][8]
  size_t gb = (size_t)(d * 32 + bt) * T * 8192;

  u16 gv[2][4];
  #pragma unroll
  for (int pp = 0; pp < 2; ++pp)
    #pragma unroll
    for (int g = 0; g < 4; ++g)
      gv[pp][g] = ginc[gb + (size_t)(brow0 + pp * 4) * 1024 + g * 256 + u];

  __syncthreads();

  for (int t = t0; t < t0 + T; ++t) {
    // ---- MFMA phase: S[brow][j] = h . Whh[j]^T, B streamed from L2 ----
    s16x8 a[8];
    #pragma unroll
    for (int kc = 0; kc < 8; ++kc)
      a[kc] = *(const s16x8*)&h_lds[(lane & 15) * 264 + kc * 32 + (lane >> 4) * 8];

    f32x4v acc[4] = {};
    s16x8 bcur[4], bnext[4];
    #pragma unroll
    for (int nf = 0; nf < 4; ++nf)
      bcur[nf] = *(const s16x8*)(wpk + (size_t)nf * 512 + lane * 8);
    #pragma unroll
    for (int kc = 0; kc < 8; ++kc) {
      if (kc < 7) {
        #pragma unroll
        for (int nf = 0; nf < 4; ++nf)
          bnext[nf] = *(const s16x8*)(wpk + (size_t)((kc + 1) * 4 + nf) * 512 + lane * 8);
      }
      #pragma unroll
      for (int nf = 0; nf < 4; ++nf)
        acc[nf] = __builtin_amdgcn_mfma_f32_16x16x32_bf16(a[kc], bcur[nf], acc[nf], 0, 0, 0);
      if (kc < 7) {
        #pragma unroll
        for (int nf = 0; nf < 4; ++nf) bcur[nf] = bnext[nf];
      }
    }
    #pragma unroll
    for (int nf = 0; nf < 4; ++nf)
      #pragma unroll
      for (int i = 0; i < 4; ++i) {
        int row = (lane >> 4) * 4 + i;
        if (row < 8)
          g_lds[row * 1028 + w * 64 + nf * 16 + (lane & 15)] = acc[nf][i];
      }
    __syncthreads();

    // ---- gate phase: each thread owns 2 (brow,u) cells ----
    int tl = t - t0;
    int tmap = d ? (255 - t) : t;
    float hn2[2];
    #pragma unroll
    for (int pp = 0; pp < 2; ++pp) {
      int br = brow0 + pp * 4;
      float si = g_lds[br * 1028 +   0 + u] + bf2f(gv[pp][0]) + bs[0];
      float sf = g_lds[br * 1028 + 256 + u] + bf2f(gv[pp][1]) + bs[1];
      float sg = g_lds[br * 1028 + 512 + u] + bf2f(gv[pp][2]) + bs[2];
      float so = g_lds[br * 1028 + 768 + u] + bf2f(gv[pp][3]) + bs[3];
      float I = 1.f / (1.f + __expf(-si));
      float F = 1.f / (1.f + __expf(-sf));
      float sgc = fminf(fmaxf(sg, -15.f), 15.f);
      float e2 = __expf(2.f * sgc);
      float G = (e2 - 1.f) / (e2 + 1.f);
      float O = 1.f / (1.f + __expf(-so));
      float cn = F * c[pp] + I * G;
      c[pp] = cn;
      float cc2 = fminf(fmaxf(cn, -15.f), 15.f);
      float ec2 = __expf(2.f * cc2);
      float hn = O * (ec2 - 1.f) / (ec2 + 1.f);
      if (tmap < lm[pp]) va[pp] += hn;
      hn2[pp] = hn;
    }
    // prefetch next step's gin
    int tln = (tl + 1 < T) ? (tl + 1) : tl;
    size_t gbn = gb + (size_t)tln * 8192;
    #pragma unroll
    for (int pp = 0; pp < 2; ++pp)
      #pragma unroll
      for (int g = 0; g < 4; ++g)
        gv[pp][g] = ginc[gbn + (size_t)(brow0 + pp * 4) * 1024 + g * 256 + u];
    // write h(t+1)
    h_lds[(brow0)     * 264 + u] = f2bf(hn2[0]);
    h_lds[(brow0 + 4) * 264 + u] = f2bf(hn2[1]);
    __syncthreads();
  }

  #pragma unroll
  for (int pp = 0; pp < 2; ++pp) {
    int br = brow0 + pp * 4;
    size_t idx = ((size_t)d * 256 + bt * 8 + br) * 256 + u;
    cstate[idx] = c[pp];
    vaccst[idx] = va[pp];
    if (t0 + T == 256) {
      int R = bt * 8 + br;
      int seq = R >> 7, bb = R & 127;
      vout[((size_t)seq * 128 + bb) * 512 + d * 256 + u] = va[pp] / (float)lm[pp];
    } else {
      hsave[idx] = h_lds[br * 264 + u];
    }
  }
}

// ---------------- MLP head ----------------
__global__ void mlp_kernel(const float* v, const float* W1, const float* b1,
                           const float* W2, const float* b2, const float* Wo, const float* bo,
                           float* out)
{
  __shared__ float vec[512];
  __shared__ float a1[512];
  __shared__ float red[4];
  int b = blockIdx.x;
  int tid = threadIdx.x;   // 256
  for (int i = tid; i < 512; i += 256)
    vec[i] = fabsf(v[(size_t)b * 512 + i] - v[(size_t)(128 + b) * 512 + i]);
  __syncthreads();
  for (int j = tid; j < 512; j += 256) {
    float s = b1[j];
    const float* wr = W1 + (size_t)j * 512;
    for (int k = 0; k < 512; ++k) s += vec[k] * wr[k];
    a1[j] = fmaxf(s, 0.f);
  }
  __syncthreads();
  float s = b2[tid];
  {
    const float* wr = W2 + (size_t)tid * 512;
    for (int k = 0; k < 512; ++k) s += a1[k] * wr[k];
  }
  float p = fmaxf(s, 0.f) * Wo[tid];
  for (int off = 32; off > 0; off >>= 1) p += __shfl_down(p, off);
  if ((tid & 63) == 0) red[tid >> 6] = p;
  __syncthreads();
  if (tid == 0) {
    float logit = red[0] + red[1] + red[2] + red[3] + bo[0];
    out[b] = logit;
    out[128 + b] = 1.f / (1.f + __expf(-logit));
  }
}

extern "C" void kernel_launch(void* const* d_in, const int* in_sizes, int n_in,
                              void* d_out, int out_size, void* d_ws, size_t ws_size,
                              hipStream_t stream)
{
  const int*   x1    = (const int*)d_in[0];
  const int*   x2    = (const int*)d_in[1];
  const int*   len1  = (const int*)d_in[2];
  const int*   len2  = (const int*)d_in[3];
  const float* emb   = (const float*)d_in[4];
  const float* wih_f = (const float*)d_in[5];
  const float* whh_f = (const float*)d_in[6];
  const float* bih_f = (const float*)d_in[7];
  const float* bhh_f = (const float*)d_in[8];
  const float* wih_b = (const float*)d_in[9];
  const float* whh_b = (const float*)d_in[10];
  const float* bih_b = (const float*)d_in[11];
  const float* bhh_b = (const float*)d_in[12];
  const float* W1    = (const float*)d_in[13];
  const float* b1    = (const float*)d_in[14];
  const float* W2    = (const float*)d_in[15];
  const float* b2    = (const float*)d_in[16];
  const float* Wo    = (const float*)d_in[17];
  const float* bo    = (const float*)d_in[18];

  char* p = (char*)d_ws;
  u16*   wih_bf = (u16*)p;          p += SZ_WIH;
  u16*   whh_pk = (u16*)p;          p += SZ_WPK;
  float* bias   = (float*)p;        p += SZ_BIAS;
  u16*   hsave  = (u16*)p;          p += SZ_HSV;
  float* cst    = (float*)p;        p += SZ_CST;
  float* vac    = (float*)p;        p += SZ_VAC;
  float* vout   = (float*)p;        p += SZ_VOUT;

  int T = 256;
  while (T > 1 && FIXED_B + (size_t)T * PER_T > ws_size) T >>= 1;
  int logT = __builtin_ctz((unsigned)T);
  u16* ec   = (u16*)p;              p += (size_t)512 * T * EPAD * 2;
  u16* ginc = (u16*)p;

  {
    int total = 2 * 1024 * EPAD + 65536 + 2 * 1024;
    prep_kernel<<<(total + 255) / 256, 256, 0, stream>>>(
        wih_f, whh_f, bih_f, bhh_f, wih_b, whh_b, bih_b, bhh_b,
        wih_bf, whh_pk, bias);
  }

  int nch = 256 / T;
  for (int ch = 0; ch < nch; ++ch) {
    int tt0 = ch * T;
    embed_chunk_kernel<<<512 * T, EPAD, 0, stream>>>(x1, x2, emb, ec, tt0, T, logT);
    gemm_chunk_kernel<<<dim3(4 * T, 8), 256, 0, stream>>>(ec, wih_bf, ginc, T, logT);
    lstm_chunk_kernel<<<64, 1024, 0, stream>>>(ginc, whh_pk, bias, hsave,
                                               cst, vac, vout, len1, len2, tt0, T);
  }

  mlp_kernel<<<128, 256, 0, stream>>>(vout, W1, b1, W2, b2, Wo, bo, (float*)d_out);
}

// Round 4
// 904.393 us; speedup vs baseline: 12.8390x; 2.5805x over previous
//
#include <hip/hip_runtime.h>
#include <hip/hip_bf16.h>
#include <math.h>

typedef unsigned short u16;
typedef short s16x8 __attribute__((ext_vector_type(8)));
typedef float f32x4v __attribute__((ext_vector_type(4)));
typedef int i32x4 __attribute__((ext_vector_type(4)));

#define EDIM 300
#define EPAD 320

// ---- fixed workspace layout (bytes) ----
static constexpr size_t SZ_WIH  = (size_t)2 * 1024 * EPAD * 2;   // bf16 [2][1024][320]
static constexpr size_t SZ_WPK  = (size_t)2 * 1024 * 256;        // i8 packed Whh frags (512 KB)
static constexpr size_t SZ_SW   = (size_t)2 * 1024 * 4;          // f32 per-row scale/127
static constexpr size_t SZ_BIAS = (size_t)2 * 1024 * 4;          // f32  [2][1024]
static constexpr size_t SZ_HSV  = (size_t)2 * 256 * 256;         // i8 h chunk-boundary save
static constexpr size_t SZ_CST  = (size_t)2 * 256 * 256 * 4;     // f32 c-state
static constexpr size_t SZ_VAC  = (size_t)2 * 256 * 256 * 4;     // f32 vacc-state
static constexpr size_t SZ_VOUT = (size_t)2 * 128 * 512 * 4;     // f32 [2][128][512]
static constexpr size_t FIXED_B = SZ_WIH + SZ_WPK + SZ_SW + SZ_BIAS + SZ_HSV + SZ_CST + SZ_VAC + SZ_VOUT;
static constexpr size_t PER_T   = (size_t)512 * EPAD * 2 + (size_t)512 * 1024 * 2;  // 1,376,256

__device__ __forceinline__ float bf2f(u16 u) {
  union { float f; unsigned int i; } v; v.i = ((unsigned int)u) << 16; return v.f;
}
__device__ __forceinline__ u16 f2bf(float f) {
  union { float f; unsigned int i; } v; v.f = f;
  unsigned int r = v.i + 0x7fffu + ((v.i >> 16) & 1u);   // RNE (finite inputs)
  return (u16)(r >> 16);
}
__device__ __forceinline__ void gload_lds16(const void* g, void* l) {
  __builtin_amdgcn_global_load_lds((const __attribute__((address_space(1))) void*)g,
                                   (__attribute__((address_space(3))) void*)l, 16, 0, 0);
}

// ---------------- prep: Wih->bf16 padded, bias sum ----------------
__global__ void prep_kernel(const float* wih_f, const float* bih_f, const float* bhh_f,
                            const float* wih_b, const float* bih_b, const float* bhh_b,
                            u16* wih_bf, float* bias)
{
  int tid = blockIdx.x * blockDim.x + threadIdx.x;
  if (tid < 2 * 1024 * EPAD) {
    int d = tid / (1024 * EPAD); int rr = tid % (1024 * EPAD);
    int j = rr / EPAD; int k = rr % EPAD;
    const float* w = d ? wih_b : wih_f;
    wih_bf[tid] = (k < EDIM) ? f2bf(w[(size_t)j * EDIM + k]) : (u16)0;
  }
  int t2 = tid - 2 * 1024 * EPAD;
  if (t2 >= 0 && t2 < 2 * 1024) {
    int d = t2 >> 10; int j = t2 & 1023;
    bias[t2] = d ? (bih_b[j] + bhh_b[j]) : (bih_f[j] + bhh_f[j]);
  }
}

// ---------------- Whh -> i8 quant + MFMA-fragment pack ----------------
// wpk layout: [d][w16][nf4][kc4][lane64][16 bytes]; entry bytes = W_q[j, kc*64+(lane>>4)*16 .. +16)
// for j = w*64 + nf*16 + (lane&15). sw[j] = rowmax/(127*127).
__global__ void whhq_kernel(const float* whh_f, const float* whh_b, char* wpk, float* sw)
{
  int j = blockIdx.x;              // 0..2047
  int lane = threadIdx.x;          // 64
  int d = j >> 10, jj = j & 1023;
  const float* src = (d ? whh_b : whh_f) + (size_t)jj * 256;
  float v[4]; float m = 0.f;
  #pragma unroll
  for (int kk = 0; kk < 4; ++kk) { v[kk] = src[lane * 4 + kk]; m = fmaxf(m, fabsf(v[kk])); }
  #pragma unroll
  for (int off = 32; off > 0; off >>= 1) m = fmaxf(m, __shfl_xor(m, off));
  float sunit = m / 127.f;
  if (sunit < 1e-30f) sunit = 1e-30f;
  unsigned int pk = 0;
  #pragma unroll
  for (int kk = 0; kk < 4; ++kk) {
    int q = (int)rintf(v[kk] / sunit);
    q = q > 127 ? 127 : (q < -127 ? -127 : q);
    pk |= ((unsigned int)(q & 255)) << (8 * kk);
  }
  size_t base = ((((size_t)(d * 16 + (jj >> 6)) * 4 + ((jj >> 4) & 3)) * 4 + (lane >> 4)) * 64
                 + ((((lane >> 2) & 3) << 4) | (jj & 15))) * 16 + (lane & 3) * 4;
  *(unsigned int*)&wpk[base] = pk;
  if (lane == 0) sw[j] = sunit / 127.f;
}

// ---------------- embedding gather for one time-chunk ----------------
__global__ void embed_chunk_kernel(const int* x1, const int* x2, const float* emb,
                                   u16* ec, int t0, int T, int logT)
{
  int row = blockIdx.x;
  int k = threadIdx.x;            // 0..319
  int R  = row & 255;
  int tl = (row >> 8) & (T - 1);
  int d  = row >> (8 + logT);
  int seq = R >> 7, b = R & 127;
  const int* x = seq ? x2 : x1;
  int t = t0 + tl;
  int tok = x[b * 256 + (d ? (255 - t) : t)];
  float v = (k < EDIM) ? emb[(size_t)tok * EDIM + k] : 0.0f;
  ec[(size_t)row * EPAD + k] = f2bf(v);
}

// ---------------- input projection GEMM for one chunk (+bias fold) ----------------
__global__ void __launch_bounds__(256, 2)
gemm_chunk_kernel(const u16* __restrict__ ec, const u16* __restrict__ wih_bf,
                  const float* __restrict__ bias, u16* __restrict__ ginc, int T, int logT)
{
  __shared__ __align__(16) u16 As[128 * 64];
  __shared__ __align__(16) u16 Bs[128 * 64];
  int m0 = blockIdx.x * 128;
  int d  = m0 >> (8 + logT);
  int n0 = blockIdx.y * 128;
  int lane = threadIdx.x & 63;
  int w = threadIdx.x >> 6;
  int wm = w >> 1, wn = w & 1;

  f32x4v acc[4][4] = {};
  const char* Abase = (const char*)ec;
  const char* Bbase = (const char*)(wih_bf + (size_t)d * 1024 * EPAD);

  int ar  = lane >> 3;
  int acb = (lane & 7) * 16;
  int sw  = ar << 4;

  for (int kt = 0; kt < 5; ++kt) {
    int k0b = kt * 128;
    #pragma unroll
    for (int i = 0; i < 4; ++i) {
      int lrow = (i * 4 + w) * 8 + ar;
      gload_lds16(Abase + (size_t)(m0 + lrow) * 640 + k0b + (acb ^ sw),
                  (char*)As + (i * 4 + w) * 1024);
      gload_lds16(Bbase + (size_t)(n0 + lrow) * 640 + k0b + (acb ^ sw),
                  (char*)Bs + (i * 4 + w) * 1024);
    }
    __syncthreads();
    #pragma unroll
    for (int kc = 0; kc < 2; ++kc) {
      s16x8 a[4], b[4];
      int cb = kc * 64 + (lane >> 4) * 16;
      #pragma unroll
      for (int mf = 0; mf < 4; ++mf) {
        int rr = wm * 64 + mf * 16 + (lane & 15);
        a[mf] = *(const s16x8*)((const char*)As + rr * 128 + (cb ^ ((rr & 7) << 4)));
      }
      #pragma unroll
      for (int nf = 0; nf < 4; ++nf) {
        int rr = wn * 64 + nf * 16 + (lane & 15);
        b[nf] = *(const s16x8*)((const char*)Bs + rr * 128 + (cb ^ ((rr & 7) << 4)));
      }
      #pragma unroll
      for (int mf = 0; mf < 4; ++mf)
        #pragma unroll
        for (int nf = 0; nf < 4; ++nf)
          acc[mf][nf] = __builtin_amdgcn_mfma_f32_16x16x32_bf16(a[mf], b[nf], acc[mf][nf], 0, 0, 0);
    }
    __syncthreads();
  }

  float bv[4];
  #pragma unroll
  for (int nf = 0; nf < 4; ++nf)
    bv[nf] = bias[d * 1024 + n0 + wn * 64 + nf * 16 + (lane & 15)];

  #pragma unroll
  for (int mf = 0; mf < 4; ++mf)
    #pragma unroll
    for (int nf = 0; nf < 4; ++nf) {
      int col = n0 + wn * 64 + nf * 16 + (lane & 15);
      #pragma unroll
      for (int i = 0; i < 4; ++i) {
        int row = m0 + wm * 64 + mf * 16 + (lane >> 4) * 4 + i;
        int R  = row & 255;
        int tl = (row >> 8) & (T - 1);
        int dd = row >> (8 + logT);
        size_t addr = ((((size_t)(dd * 32 + (R >> 3))) * T + tl) * 8 + (R & 7)) * 1024 + col;
        ginc[addr] = f2bf(acc[mf][nf][i] + bv[nf]);
      }
    }
}

// ---------------- recurrent bi-LSTM: Whh register-resident as i8 frags ----------------
// 64 blocks = 2 dirs x 32 batch-tiles (8 rows). 16 waves; wave w owns j in [w*64,(w+1)*64).
// Zero per-step weight traffic; gin streamed (prefetched) from HBM.
__global__ void __launch_bounds__(1024)
lstm_chunk_kernel(const u16* __restrict__ ginc, const i32x4* __restrict__ wpk,
                  const float* __restrict__ sw, char* hsave,
                  float* cstate, float* vaccst, float* vout,
                  const int* len1, const int* len2, int t0, int T)
{
  __shared__ __align__(16) char h_lds[16 * 272];    // i8 [16 rows (8 real)][256 k] +16 pad
  __shared__ float g_lds[8 * 1028];                 // f32 [8 brow][1024 j] +4 pad

  const int bid = blockIdx.x;
  const int d = bid >> 5, bt = bid & 31;
  const int tid = threadIdx.x;
  const int lane = tid & 63, w = tid >> 6;          // wave 0..15

  // ---- Whh i8 fragments -> 64 VGPRs; per-column scales -> 4 VGPRs ----
  i32x4 bfr[4][4];
  #pragma unroll
  for (int nf = 0; nf < 4; ++nf)
    #pragma unroll
    for (int kc = 0; kc < 4; ++kc)
      bfr[nf][kc] = wpk[(((size_t)(d * 16 + w) * 4 + nf) * 4 + kc) * 64 + lane];
  float swl[4];
  #pragma unroll
  for (int nf = 0; nf < 4; ++nf)
    swl[nf] = sw[d * 1024 + w * 64 + nf * 16 + (lane & 15)];

  // ---- init h ----
  for (int i = tid; i < 16 * 272 / 4; i += 1024) ((unsigned int*)h_lds)[i] = 0u;
  __syncthreads();
  if (t0 > 0) {
    int idx = tid * 2;               // 2048 bytes: 8 rows x 256
    int row = idx >> 8, col = idx & 255;
    *(char2*)&h_lds[row * 272 + col] =
        *(const char2*)&hsave[((size_t)d * 256 + bt * 8 + row) * 256 + col];
  }

  const int brow0 = tid >> 8;        // 0..3 (pairs brow0, brow0+4)
  const int u = tid & 255;
  int lm[2];
  float c[2] = {0.f, 0.f}, va[2] = {0.f, 0.f};
  #pragma unroll
  for (int pp = 0; pp < 2; ++pp) {
    int R = bt * 8 + brow0 + pp * 4;
    lm[pp] = ((R >> 7) ? len2 : len1)[R & 127] - 1;
  }
  if (t0 > 0) {
    #pragma unroll
    for (int pp = 0; pp < 2; ++pp) {
      size_t idx = ((size_t)d * 256 + bt * 8 + brow0 + pp * 4) * 256 + u;
      c[pp] = cstate[idx];
      va[pp] = vaccst[idx];
    }
  }

  size_t gb = (size_t)(d * 32 + bt) * T * 8192;
  u16 gv[2][4];
  #pragma unroll
  for (int pp = 0; pp < 2; ++pp) {
    size_t a0 = gb + (size_t)(brow0 + pp * 4) * 1024 + u;
    gv[pp][0] = ginc[a0];       gv[pp][1] = ginc[a0 + 256];
    gv[pp][2] = ginc[a0 + 512]; gv[pp][3] = ginc[a0 + 768];
  }
  __syncthreads();

  const bool final_chunk = (t0 + T == 256);
  for (int t = t0; t < t0 + T; ++t) {
    // ---- MFMA phase: preact_hh[brow][j] = (h_i8 . Whh_i8[j]) * sw[j] ----
    i32x4 a[4];
    #pragma unroll
    for (int kc = 0; kc < 4; ++kc)
      a[kc] = *(const i32x4*)&h_lds[(lane & 15) * 272 + kc * 64 + (lane >> 4) * 16];
    #pragma unroll
    for (int nf = 0; nf < 4; ++nf) {
      i32x4 acc = {0, 0, 0, 0};
      #pragma unroll
      for (int kc = 0; kc < 4; ++kc)
        acc = __builtin_amdgcn_mfma_i32_16x16x64_i8(a[kc], bfr[nf][kc], acc, 0, 0, 0);
      #pragma unroll
      for (int i = 0; i < 4; ++i) {
        int row = (lane >> 4) * 4 + i;
        if (row < 8)
          g_lds[row * 1028 + w * 64 + nf * 16 + (lane & 15)] = (float)acc[i] * swl[nf];
      }
    }
    __syncthreads();

    // ---- gate phase ----
    float gx[2][4];
    #pragma unroll
    for (int pp = 0; pp < 2; ++pp)
      #pragma unroll
      for (int g = 0; g < 4; ++g) gx[pp][g] = bf2f(gv[pp][g]);
    int tl = t - t0;
    int tln = (tl + 1 < T) ? (tl + 1) : tl;
    size_t gbn = gb + (size_t)tln * 8192;
    #pragma unroll
    for (int pp = 0; pp < 2; ++pp) {
      size_t a0 = gbn + (size_t)(brow0 + pp * 4) * 1024 + u;
      gv[pp][0] = ginc[a0];       gv[pp][1] = ginc[a0 + 256];
      gv[pp][2] = ginc[a0 + 512]; gv[pp][3] = ginc[a0 + 768];
    }
    int tmap = d ? (255 - t) : t;
    #pragma unroll
    for (int pp = 0; pp < 2; ++pp) {
      int br = brow0 + pp * 4;
      float si = g_lds[br * 1028 +       u] + gx[pp][0];
      float sf = g_lds[br * 1028 + 256 + u] + gx[pp][1];
      float sg = g_lds[br * 1028 + 512 + u] + gx[pp][2];
      float so = g_lds[br * 1028 + 768 + u] + gx[pp][3];
      float I = 1.f / (1.f + __expf(-si));
      float F = 1.f / (1.f + __expf(-sf));
      float sgc = fminf(fmaxf(sg, -15.f), 15.f);
      float e2 = __expf(2.f * sgc);
      float G = (e2 - 1.f) / (e2 + 1.f);
      float O = 1.f / (1.f + __expf(-so));
      float cn = F * c[pp] + I * G;
      c[pp] = cn;
      float cc2 = fminf(fmaxf(cn, -15.f), 15.f);
      float ec2 = __expf(2.f * cc2);
      float hn = O * (ec2 - 1.f) / (ec2 + 1.f);
      if (tmap < lm[pp]) va[pp] += hn;
      int q = (int)rintf(fminf(fmaxf(hn, -0.9999f), 0.9999f) * 127.f);
      h_lds[br * 272 + u] = (char)q;
      if (!final_chunk && t == t0 + T - 1)
        hsave[((size_t)d * 256 + bt * 8 + br) * 256 + u] = (char)q;
    }
    __syncthreads();
  }

  #pragma unroll
  for (int pp = 0; pp < 2; ++pp) {
    int br = brow0 + pp * 4;
    size_t idx = ((size_t)d * 256 + bt * 8 + br) * 256 + u;
    cstate[idx] = c[pp];
    vaccst[idx] = va[pp];
    if (final_chunk) {
      int R = bt * 8 + br;
      int seq = R >> 7, bb = R & 127;
      vout[((size_t)seq * 128 + bb) * 512 + d * 256 + u] = va[pp] / (float)lm[pp];
    }
  }
}

// ---------------- MLP head ----------------
__global__ void mlp_kernel(const float* v, const float* W1, const float* b1,
                           const float* W2, const float* b2, const float* Wo, const float* bo,
                           float* out)
{
  __shared__ float vec[512];
  __shared__ float a1[512];
  __shared__ float red[4];
  int b = blockIdx.x;
  int tid = threadIdx.x;   // 256
  for (int i = tid; i < 512; i += 256)
    vec[i] = fabsf(v[(size_t)b * 512 + i] - v[(size_t)(128 + b) * 512 + i]);
  __syncthreads();
  for (int j = tid; j < 512; j += 256) {
    float s = b1[j];
    const float* wr = W1 + (size_t)j * 512;
    for (int k = 0; k < 512; ++k) s += vec[k] * wr[k];
    a1[j] = fmaxf(s, 0.f);
  }
  __syncthreads();
  float s = b2[tid];
  {
    const float* wr = W2 + (size_t)tid * 512;
    for (int k = 0; k < 512; ++k) s += a1[k] * wr[k];
  }
  float p = fmaxf(s, 0.f) * Wo[tid];
  for (int off = 32; off > 0; off >>= 1) p += __shfl_down(p, off);
  if ((tid & 63) == 0) red[tid >> 6] = p;
  __syncthreads();
  if (tid == 0) {
    float logit = red[0] + red[1] + red[2] + red[3] + bo[0];
    out[b] = logit;
    out[128 + b] = 1.f / (1.f + __expf(-logit));
  }
}

extern "C" void kernel_launch(void* const* d_in, const int* in_sizes, int n_in,
                              void* d_out, int out_size, void* d_ws, size_t ws_size,
                              hipStream_t stream)
{
  const int*   x1    = (const int*)d_in[0];
  const int*   x2    = (const int*)d_in[1];
  const int*   len1  = (const int*)d_in[2];
  const int*   len2  = (const int*)d_in[3];
  const float* emb   = (const float*)d_in[4];
  const float* wih_f = (const float*)d_in[5];
  const float* whh_f = (const float*)d_in[6];
  const float* bih_f = (const float*)d_in[7];
  const float* bhh_f = (const float*)d_in[8];
  const float* wih_b = (const float*)d_in[9];
  const float* whh_b = (const float*)d_in[10];
  const float* bih_b = (const float*)d_in[11];
  const float* bhh_b = (const float*)d_in[12];
  const float* W1    = (const float*)d_in[13];
  const float* b1    = (const float*)d_in[14];
  const float* W2    = (const float*)d_in[15];
  const float* b2    = (const float*)d_in[16];
  const float* Wo    = (const float*)d_in[17];
  const float* bo    = (const float*)d_in[18];

  char* p = (char*)d_ws;
  u16*   wih_bf = (u16*)p;          p += SZ_WIH;
  char*  wpk    = (char*)p;         p += SZ_WPK;
  float* swp    = (float*)p;        p += SZ_SW;
  float* bias   = (float*)p;        p += SZ_BIAS;
  char*  hsave  = (char*)p;         p += SZ_HSV;
  float* cst    = (float*)p;        p += SZ_CST;
  float* vac    = (float*)p;        p += SZ_VAC;
  float* vout   = (float*)p;        p += SZ_VOUT;

  int T = 256;
  while (T > 1 && FIXED_B + (size_t)T * PER_T > ws_size) T >>= 1;
  int logT = __builtin_ctz((unsigned)T);
  u16* ec   = (u16*)p;              p += (size_t)512 * T * EPAD * 2;
  u16* ginc = (u16*)p;

  {
    int total = 2 * 1024 * EPAD + 2 * 1024;
    prep_kernel<<<(total + 255) / 256, 256, 0, stream>>>(
        wih_f, bih_f, bhh_f, wih_b, bih_b, bhh_b, wih_bf, bias);
  }
  whhq_kernel<<<2048, 64, 0, stream>>>(whh_f, whh_b, wpk, swp);

  int nch = 256 / T;
  for (int ch = 0; ch < nch; ++ch) {
    int tt0 = ch * T;
    embed_chunk_kernel<<<512 * T, EPAD, 0, stream>>>(x1, x2, emb, ec, tt0, T, logT);
    gemm_chunk_kernel<<<dim3(4 * T, 8), 256, 0, stream>>>(ec, wih_bf, bias, ginc, T, logT);
    lstm_chunk_kernel<<<64, 1024, 0, stream>>>(ginc, (const i32x4*)wpk, swp, hsave,
                                               cst, vac, vout, len1, len2, tt0, T);
  }

  mlp_kernel<<<128, 256, 0, stream>>>(vout, W1, b1, W2, b2, Wo, bo, (float*)d_out);
}

// Round 5
// 783.101 us; speedup vs baseline: 14.8276x; 1.1549x over previous
//
#include <hip/hip_runtime.h>
#include <hip/hip_bf16.h>
#include <math.h>

typedef unsigned short u16;
typedef short s16x8 __attribute__((ext_vector_type(8)));
typedef float f32x4v __attribute__((ext_vector_type(4)));
typedef int i32x4 __attribute__((ext_vector_type(4)));
typedef unsigned short u16x4 __attribute__((ext_vector_type(4)));

#define EDIM 300
#define EPAD 320

// ---- fixed workspace layout (bytes) ----
static constexpr size_t SZ_WIH  = (size_t)2 * 1024 * EPAD * 2;   // bf16 [2][1024][320]
static constexpr size_t SZ_WPK  = (size_t)2 * 1024 * 256;        // i8 packed Whh frags (512 KB)
static constexpr size_t SZ_SW   = (size_t)2 * 1024 * 4;          // f32 per-row scale
static constexpr size_t SZ_BIAS = (size_t)2 * 1024 * 4;          // f32  [2][1024]
static constexpr size_t SZ_HSV  = (size_t)2 * 256 * 256;         // i8 h chunk-boundary save
static constexpr size_t SZ_CST  = (size_t)2 * 256 * 256 * 4;     // f32 c-state
static constexpr size_t SZ_VAC  = (size_t)2 * 256 * 256 * 4;     // f32 vacc-state
static constexpr size_t SZ_VOUT = (size_t)2 * 128 * 512 * 4;     // f32 [2][128][512]
static constexpr size_t SZ_PAD  = 8192;                          // gin prefetch overrun pad
static constexpr size_t FIXED_B = SZ_WIH + SZ_WPK + SZ_SW + SZ_BIAS + SZ_HSV + SZ_CST + SZ_VAC + SZ_VOUT + SZ_PAD;
static constexpr size_t PER_T   = (size_t)512 * EPAD * 2 + (size_t)512 * 1024 * 2;  // ec + ginc per step

__device__ __forceinline__ float bf2f(u16 u) {
  union { float f; unsigned int i; } v; v.i = ((unsigned int)u) << 16; return v.f;
}
__device__ __forceinline__ u16 f2bf(float f) {
  union { float f; unsigned int i; } v; v.f = f;
  unsigned int r = v.i + 0x7fffu + ((v.i >> 16) & 1u);   // RNE (finite inputs)
  return (u16)(r >> 16);
}
__device__ __forceinline__ void gload_lds16(const void* g, void* l) {
  __builtin_amdgcn_global_load_lds((const __attribute__((address_space(1))) void*)g,
                                   (__attribute__((address_space(3))) void*)l, 16, 0, 0);
}
// LDS-release barrier: order LDS ops across waves WITHOUT draining vmcnt
__device__ __forceinline__ void lds_barrier() {
  asm volatile("s_waitcnt lgkmcnt(0)" ::: "memory");
  __builtin_amdgcn_s_barrier();
}

// ---------------- prep: Wih->bf16 padded, bias sum ----------------
__global__ void prep_kernel(const float* wih_f, const float* bih_f, const float* bhh_f,
                            const float* wih_b, const float* bih_b, const float* bhh_b,
                            u16* wih_bf, float* bias)
{
  int tid = blockIdx.x * blockDim.x + threadIdx.x;
  if (tid < 2 * 1024 * EPAD) {
    int d = tid / (1024 * EPAD); int rr = tid % (1024 * EPAD);
    int j = rr / EPAD; int k = rr % EPAD;
    const float* w = d ? wih_b : wih_f;
    wih_bf[tid] = (k < EDIM) ? f2bf(w[(size_t)j * EDIM + k]) : (u16)0;
  }
  int t2 = tid - 2 * 1024 * EPAD;
  if (t2 >= 0 && t2 < 2 * 1024) {
    int d = t2 >> 10; int j = t2 & 1023;
    bias[t2] = d ? (bih_b[j] + bhh_b[j]) : (bih_f[j] + bhh_f[j]);
  }
}

// ---------------- Whh -> i8 quant + MFMA-fragment pack (verified in R4) ----------------
__global__ void whhq_kernel(const float* whh_f, const float* whh_b, char* wpk, float* sw)
{
  int j = blockIdx.x;              // 0..2047
  int lane = threadIdx.x;          // 64
  int d = j >> 10, jj = j & 1023;
  const float* src = (d ? whh_b : whh_f) + (size_t)jj * 256;
  float v[4]; float m = 0.f;
  #pragma unroll
  for (int kk = 0; kk < 4; ++kk) { v[kk] = src[lane * 4 + kk]; m = fmaxf(m, fabsf(v[kk])); }
  #pragma unroll
  for (int off = 32; off > 0; off >>= 1) m = fmaxf(m, __shfl_xor(m, off));
  float sunit = m / 127.f;
  if (sunit < 1e-30f) sunit = 1e-30f;
  unsigned int pk = 0;
  #pragma unroll
  for (int kk = 0; kk < 4; ++kk) {
    int q = (int)rintf(v[kk] / sunit);
    q = q > 127 ? 127 : (q < -127 ? -127 : q);
    pk |= ((unsigned int)(q & 255)) << (8 * kk);
  }
  size_t base = ((((size_t)(d * 16 + (jj >> 6)) * 4 + ((jj >> 4) & 3)) * 4 + (lane >> 4)) * 64
                 + ((((lane >> 2) & 3) << 4) | (jj & 15))) * 16 + (lane & 3) * 4;
  *(unsigned int*)&wpk[base] = pk;
  if (lane == 0) sw[j] = sunit / 127.f;
}

// ---------------- embedding gather for one time-chunk ----------------
__global__ void embed_chunk_kernel(const int* x1, const int* x2, const float* emb,
                                   u16* ec, int t0, int T, int logT)
{
  int row = blockIdx.x;
  int k = threadIdx.x;            // 0..319
  int R  = row & 255;
  int tl = (row >> 8) & (T - 1);
  int d  = row >> (8 + logT);
  int seq = R >> 7, b = R & 127;
  const int* x = seq ? x2 : x1;
  int t = t0 + tl;
  int tok = x[b * 256 + (d ? (255 - t) : t)];
  float v = (k < EDIM) ? emb[(size_t)tok * EDIM + k] : 0.0f;
  ec[(size_t)row * EPAD + k] = f2bf(v);
}

// ---------------- input projection GEMM for one chunk (+bias fold) ----------------
// Epilogue writes gate-interleaved layout: [(d*64+bt4)*T + tl][rt4][u256][g4] u16
__global__ void __launch_bounds__(256, 2)
gemm_chunk_kernel(const u16* __restrict__ ec, const u16* __restrict__ wih_bf,
                  const float* __restrict__ bias, u16* __restrict__ ginc, int T, int logT)
{
  __shared__ __align__(16) u16 As[128 * 64];
  __shared__ __align__(16) u16 Bs[128 * 64];
  int m0 = blockIdx.x * 128;
  int d  = m0 >> (8 + logT);
  int n0 = blockIdx.y * 128;
  int lane = threadIdx.x & 63;
  int w = threadIdx.x >> 6;
  int wm = w >> 1, wn = w & 1;

  f32x4v acc[4][4] = {};
  const char* Abase = (const char*)ec;
  const char* Bbase = (const char*)(wih_bf + (size_t)d * 1024 * EPAD);

  int ar  = lane >> 3;
  int acb = (lane & 7) * 16;
  int sw  = ar << 4;

  for (int kt = 0; kt < 5; ++kt) {
    int k0b = kt * 128;
    #pragma unroll
    for (int i = 0; i < 4; ++i) {
      int lrow = (i * 4 + w) * 8 + ar;
      gload_lds16(Abase + (size_t)(m0 + lrow) * 640 + k0b + (acb ^ sw),
                  (char*)As + (i * 4 + w) * 1024);
      gload_lds16(Bbase + (size_t)(n0 + lrow) * 640 + k0b + (acb ^ sw),
                  (char*)Bs + (i * 4 + w) * 1024);
    }
    __syncthreads();
    #pragma unroll
    for (int kc = 0; kc < 2; ++kc) {
      s16x8 a[4], b[4];
      int cb = kc * 64 + (lane >> 4) * 16;
      #pragma unroll
      for (int mf = 0; mf < 4; ++mf) {
        int rr = wm * 64 + mf * 16 + (lane & 15);
        a[mf] = *(const s16x8*)((const char*)As + rr * 128 + (cb ^ ((rr & 7) << 4)));
      }
      #pragma unroll
      for (int nf = 0; nf < 4; ++nf) {
        int rr = wn * 64 + nf * 16 + (lane & 15);
        b[nf] = *(const s16x8*)((const char*)Bs + rr * 128 + (cb ^ ((rr & 7) << 4)));
      }
      #pragma unroll
      for (int mf = 0; mf < 4; ++mf)
        #pragma unroll
        for (int nf = 0; nf < 4; ++nf)
          acc[mf][nf] = __builtin_amdgcn_mfma_f32_16x16x32_bf16(a[mf], b[nf], acc[mf][nf], 0, 0, 0);
    }
    __syncthreads();
  }

  float bv[4];
  #pragma unroll
  for (int nf = 0; nf < 4; ++nf)
    bv[nf] = bias[d * 1024 + n0 + wn * 64 + nf * 16 + (lane & 15)];

  #pragma unroll
  for (int mf = 0; mf < 4; ++mf)
    #pragma unroll
    for (int nf = 0; nf < 4; ++nf) {
      int col = n0 + wn * 64 + nf * 16 + (lane & 15);
      int u = col & 255, g = col >> 8;
      #pragma unroll
      for (int i = 0; i < 4; ++i) {
        int row = m0 + wm * 64 + mf * 16 + (lane >> 4) * 4 + i;
        int R  = row & 255;
        int tl = (row >> 8) & (T - 1);
        int dd = row >> (8 + logT);
        size_t addr = ((((size_t)(dd * 64 + (R >> 2)) * T + tl) * 4 + (R & 3)) * 256 + u) * 4 + g;
        ginc[addr] = f2bf(acc[mf][nf][i] + bv[nf]);
      }
    }
}

// ---------------- recurrent bi-LSTM: 128 blocks = 2 dirs x 64 tiles of 4 rows ----------------
// Whh i8 register-resident; gin packed (ushort4/cell); raw lgkm-only barriers so the
// gin prefetch stays in flight across steps.
__global__ void __launch_bounds__(1024)
lstm_chunk_kernel(const u16* __restrict__ ginc, const i32x4* __restrict__ wpk,
                  const float* __restrict__ sw, char* hsave,
                  float* cstate, float* vaccst, float* vout,
                  const int* len1, const int* len2, int t0, int T)
{
  __shared__ __align__(16) char h_lds[16 * 272];    // i8 [16 rows (4 real)][256 k] +16 pad
  __shared__ float g_lds[4 * 1028];                 // f32 [4 rt][1024 j] +4 pad

  const int bid = blockIdx.x;
  const int d = bid >> 6, bt = bid & 63;
  const int tid = threadIdx.x;
  const int lane = tid & 63, w = tid >> 6;          // wave 0..15

  // ---- Whh i8 fragments -> 64 VGPRs; per-column scales ----
  i32x4 bfr[4][4];
  #pragma unroll
  for (int nf = 0; nf < 4; ++nf)
    #pragma unroll
    for (int kc = 0; kc < 4; ++kc)
      bfr[nf][kc] = wpk[(((size_t)(d * 16 + w) * 4 + nf) * 4 + kc) * 64 + lane];
  float swl[4];
  #pragma unroll
  for (int nf = 0; nf < 4; ++nf)
    swl[nf] = sw[d * 1024 + w * 64 + nf * 16 + (lane & 15)];

  // ---- init h (rows 4-15 stay zero forever) ----
  for (int i = tid; i < 16 * 272 / 4; i += 1024) ((unsigned int*)h_lds)[i] = 0u;
  __syncthreads();

  const int rt = tid >> 8;           // 0..3  (row in tile)
  const int u  = tid & 255;          // hidden unit
  const int R  = bt * 4 + rt;        // global row: seq = R>>7, b = R&127
  const size_t sidx = ((size_t)d * 256 + R) * 256 + u;

  if (t0 > 0) h_lds[rt * 272 + u] = hsave[sidx];

  int lm = ((R >> 7) ? len2 : len1)[R & 127] - 1;
  float c = 0.f, va = 0.f;
  if (t0 > 0) { c = cstate[sidx]; va = vaccst[sidx]; }

  // gin pointer: cell stride 4 u16, step stride 4096 u16
  const u16* gp = ginc + ((size_t)(d * 64 + bt) * T) * 4096 + ((size_t)rt * 256 + u) * 4;
  u16x4 gv = *(const u16x4*)gp;
  gp += 4096;
  __syncthreads();

  const bool final_chunk = (t0 + T == 256);
  const int tlast = t0 + T - 1;

  for (int t = t0; t < t0 + T; ++t) {
    // prefetch next step's gates (flies across both barriers)
    u16x4 gvn = *(const u16x4*)gp;
    gp += 4096;

    // ---- MFMA phase: preact_hh[rt][j] = (h_i8 . Whh_i8[j]) * sw[j] ----
    i32x4 a[4];
    #pragma unroll
    for (int kc = 0; kc < 4; ++kc)
      a[kc] = *(const i32x4*)&h_lds[(lane & 15) * 272 + kc * 64 + (lane >> 4) * 16];
    #pragma unroll
    for (int nf = 0; nf < 4; ++nf) {
      i32x4 acc = {0, 0, 0, 0};
      #pragma unroll
      for (int kc = 0; kc < 4; ++kc)
        acc = __builtin_amdgcn_mfma_i32_16x16x64_i8(a[kc], bfr[nf][kc], acc, 0, 0, 0);
      if (lane < 16) {
        #pragma unroll
        for (int i = 0; i < 4; ++i)
          g_lds[i * 1028 + w * 64 + nf * 16 + lane] = (float)acc[i] * swl[nf];
      }
    }
    lds_barrier();

    // ---- gate phase: 1 cell (rt,u) per thread ----
    float si = g_lds[rt * 1028 +       u] + bf2f(gv[0]);
    float sf = g_lds[rt * 1028 + 256 + u] + bf2f(gv[1]);
    float sg = g_lds[rt * 1028 + 512 + u] + bf2f(gv[2]);
    float so = g_lds[rt * 1028 + 768 + u] + bf2f(gv[3]);
    float I = __builtin_amdgcn_rcpf(1.f + __expf(-si));
    float F = __builtin_amdgcn_rcpf(1.f + __expf(-sf));
    float sgc = fminf(fmaxf(sg, -15.f), 15.f);
    float G = 1.f - 2.f * __builtin_amdgcn_rcpf(__expf(2.f * sgc) + 1.f);
    float O = __builtin_amdgcn_rcpf(1.f + __expf(-so));
    float cn = F * c + I * G;
    c = cn;
    float cc2 = fminf(fmaxf(cn, -15.f), 15.f);
    float hn = O * (1.f - 2.f * __builtin_amdgcn_rcpf(__expf(2.f * cc2) + 1.f));
    int tmap = d ? (255 - t) : t;
    if (tmap < lm) va += hn;
    int q = (int)rintf(fminf(fmaxf(hn, -0.9999f), 0.9999f) * 127.f);
    h_lds[rt * 272 + u] = (char)q;
    if (!final_chunk && t == tlast) hsave[sidx] = (char)q;
    gv = gvn;
    lds_barrier();
  }

  cstate[sidx] = c;
  vaccst[sidx] = va;
  if (final_chunk) {
    int seq = R >> 7, bb = R & 127;
    vout[((size_t)seq * 128 + bb) * 512 + d * 256 + u] = va / (float)lm;
  }
}

// ---------------- MLP head ----------------
__global__ void mlp_kernel(const float* v, const float* W1, const float* b1,
                           const float* W2, const float* b2, const float* Wo, const float* bo,
                           float* out)
{
  __shared__ float vec[512];
  __shared__ float a1[512];
  __shared__ float red[4];
  int b = blockIdx.x;
  int tid = threadIdx.x;   // 256
  for (int i = tid; i < 512; i += 256)
    vec[i] = fabsf(v[(size_t)b * 512 + i] - v[(size_t)(128 + b) * 512 + i]);
  __syncthreads();
  for (int j = tid; j < 512; j += 256) {
    float s = b1[j];
    const float* wr = W1 + (size_t)j * 512;
    for (int k = 0; k < 512; ++k) s += vec[k] * wr[k];
    a1[j] = fmaxf(s, 0.f);
  }
  __syncthreads();
  float s = b2[tid];
  {
    const float* wr = W2 + (size_t)tid * 512;
    for (int k = 0; k < 512; ++k) s += a1[k] * wr[k];
  }
  float p = fmaxf(s, 0.f) * Wo[tid];
  for (int off = 32; off > 0; off >>= 1) p += __shfl_down(p, off);
  if ((tid & 63) == 0) red[tid >> 6] = p;
  __syncthreads();
  if (tid == 0) {
    float logit = red[0] + red[1] + red[2] + red[3] + bo[0];
    out[b] = logit;
    out[128 + b] = 1.f / (1.f + __expf(-logit));
  }
}

extern "C" void kernel_launch(void* const* d_in, const int* in_sizes, int n_in,
                              void* d_out, int out_size, void* d_ws, size_t ws_size,
                              hipStream_t stream)
{
  const int*   x1    = (const int*)d_in[0];
  const int*   x2    = (const int*)d_in[1];
  const int*   len1  = (const int*)d_in[2];
  const int*   len2  = (const int*)d_in[3];
  const float* emb   = (const float*)d_in[4];
  const float* wih_f = (const float*)d_in[5];
  const float* whh_f = (const float*)d_in[6];
  const float* bih_f = (const float*)d_in[7];
  const float* bhh_f = (const float*)d_in[8];
  const float* wih_b = (const float*)d_in[9];
  const float* whh_b = (const float*)d_in[10];
  const float* bih_b = (const float*)d_in[11];
  const float* bhh_b = (const float*)d_in[12];
  const float* W1    = (const float*)d_in[13];
  const float* b1    = (const float*)d_in[14];
  const float* W2    = (const float*)d_in[15];
  const float* b2    = (const float*)d_in[16];
  const float* Wo    = (const float*)d_in[17];
  const float* bo    = (const float*)d_in[18];

  char* p = (char*)d_ws;
  u16*   wih_bf = (u16*)p;          p += SZ_WIH;
  char*  wpk    = (char*)p;         p += SZ_WPK;
  float* swp    = (float*)p;        p += SZ_SW;
  float* bias   = (float*)p;        p += SZ_BIAS;
  char*  hsave  = (char*)p;         p += SZ_HSV;
  float* cst    = (float*)p;        p += SZ_CST;
  float* vac    = (float*)p;        p += SZ_VAC;
  float* vout   = (float*)p;        p += SZ_VOUT;

  int T = 256;
  while (T > 1 && FIXED_B + (size_t)T * PER_T > ws_size) T >>= 1;
  int logT = __builtin_ctz((unsigned)T);
  u16* ec   = (u16*)p;              p += (size_t)512 * T * EPAD * 2;
  u16* ginc = (u16*)p;              // [ (d*64+bt)*T + tl ][4 rt][256 u][4 g] u16, +8KB pad

  {
    int total = 2 * 1024 * EPAD + 2 * 1024;
    prep_kernel<<<(total + 255) / 256, 256, 0, stream>>>(
        wih_f, bih_f, bhh_f, wih_b, bih_b, bhh_b, wih_bf, bias);
  }
  whhq_kernel<<<2048, 64, 0, stream>>>(whh_f, whh_b, wpk, swp);

  int nch = 256 / T;
  for (int ch = 0; ch < nch; ++ch) {
    int tt0 = ch * T;
    embed_chunk_kernel<<<512 * T, EPAD, 0, stream>>>(x1, x2, emb, ec, tt0, T, logT);
    gemm_chunk_kernel<<<dim3(4 * T, 8), 256, 0, stream>>>(ec, wih_bf, bias, ginc, T, logT);
    lstm_chunk_kernel<<<128, 1024, 0, stream>>>(ginc, (const i32x4*)wpk, swp, hsave,
                                                cst, vac, vout, len1, len2, tt0, T);
  }

  mlp_kernel<<<128, 256, 0, stream>>>(vout, W1, b1, W2, b2, Wo, bo, (float*)d_out);
}

// Round 6
// 566.982 us; speedup vs baseline: 20.4795x; 1.3812x over previous
//
#include <hip/hip_runtime.h>
#include <hip/hip_bf16.h>
#include <math.h>

typedef unsigned short u16;
typedef short s16x8 __attribute__((ext_vector_type(8)));
typedef float f32x4v __attribute__((ext_vector_type(4)));
typedef int i32x4 __attribute__((ext_vector_type(4)));

#define EDIM 300
#define EPAD 320
#define VOCAB 50000

// ---- fixed workspace layout (bytes) ----
static constexpr size_t SZ_WIH  = (size_t)2 * 1024 * EPAD * 2;   // bf16 [2][1024][320]
static constexpr size_t SZ_WPK  = (size_t)2 * 1024 * 256;        // i8 packed Whh frags
static constexpr size_t SZ_SW   = (size_t)2 * 1024 * 4;          // f32 per-row scale
static constexpr size_t SZ_BIAS = (size_t)2 * 1024 * 4;          // f32  [2][1024]
static constexpr size_t SZ_HSV  = (size_t)2 * 256 * 256;         // i8 h chunk-boundary save
static constexpr size_t SZ_CST  = (size_t)2 * 256 * 256 * 4;     // f32 c-state
static constexpr size_t SZ_VAC  = (size_t)2 * 256 * 256 * 4;     // f32 vacc-state
static constexpr size_t SZ_VOUT = (size_t)2 * 128 * 512 * 4;     // f32 [2][128][512]
static constexpr size_t SZ_EMB  = (size_t)VOCAB * EPAD * 2;      // bf16 emb table padded (32 MB)
static constexpr size_t FIXED_B = SZ_WIH + SZ_WPK + SZ_SW + SZ_BIAS + SZ_HSV + SZ_CST + SZ_VAC + SZ_VOUT + SZ_EMB;
static constexpr size_t PER_T   = (size_t)512 * 1024 * 2;        // ginc per step (1 MB)

__device__ __forceinline__ float bf2f(u16 u) {
  union { float f; unsigned int i; } v; v.i = ((unsigned int)u) << 16; return v.f;
}
__device__ __forceinline__ u16 f2bf(float f) {
  union { float f; unsigned int i; } v; v.f = f;
  unsigned int r = v.i + 0x7fffu + ((v.i >> 16) & 1u);   // RNE (finite inputs)
  return (u16)(r >> 16);
}
__device__ __forceinline__ void gload_lds16(const void* g, void* l) {
  __builtin_amdgcn_global_load_lds((const __attribute__((address_space(1))) void*)g,
                                   (__attribute__((address_space(3))) void*)l, 16, 0, 0);
}
// order LDS ops across waves WITHOUT draining vmcnt (global prefetches keep flying)
__device__ __forceinline__ void lds_barrier() {
  asm volatile("s_waitcnt lgkmcnt(0)" ::: "memory");
  __builtin_amdgcn_s_barrier();
}

// ---------------- prep: Wih->bf16 padded, bias sum ----------------
__global__ void prep_kernel(const float* wih_f, const float* bih_f, const float* bhh_f,
                            const float* wih_b, const float* bih_b, const float* bhh_b,
                            u16* wih_bf, float* bias)
{
  int tid = blockIdx.x * blockDim.x + threadIdx.x;
  if (tid < 2 * 1024 * EPAD) {
    int d = tid / (1024 * EPAD); int rr = tid % (1024 * EPAD);
    int j = rr / EPAD; int k = rr % EPAD;
    const float* w = d ? wih_b : wih_f;
    wih_bf[tid] = (k < EDIM) ? f2bf(w[(size_t)j * EDIM + k]) : (u16)0;
  }
  int t2 = tid - 2 * 1024 * EPAD;
  if (t2 >= 0 && t2 < 2 * 1024) {
    int d = t2 >> 10; int j = t2 & 1023;
    bias[t2] = d ? (bih_b[j] + bhh_b[j]) : (bih_f[j] + bhh_f[j]);
  }
}

// ---------------- emb -> bf16, K padded 300->320 (one-time) ----------------
__global__ void embconv_kernel(const float* emb, u16* embbf)
{
  int r = blockIdx.x;
  int k = threadIdx.x;     // 320
  embbf[(size_t)r * EPAD + k] = (k < EDIM) ? f2bf(emb[(size_t)r * EDIM + k]) : (u16)0;
}

// ---------------- Whh -> i8 quant + MFMA-fragment pack (verified R4/R5) ----------------
__global__ void whhq_kernel(const float* whh_f, const float* whh_b, char* wpk, float* sw)
{
  int j = blockIdx.x;              // 0..2047
  int lane = threadIdx.x;          // 64
  int d = j >> 10, jj = j & 1023;
  const float* src = (d ? whh_b : whh_f) + (size_t)jj * 256;
  float v[4]; float m = 0.f;
  #pragma unroll
  for (int kk = 0; kk < 4; ++kk) { v[kk] = src[lane * 4 + kk]; m = fmaxf(m, fabsf(v[kk])); }
  #pragma unroll
  for (int off = 32; off > 0; off >>= 1) m = fmaxf(m, __shfl_xor(m, off));
  float sunit = m / 127.f;
  if (sunit < 1e-30f) sunit = 1e-30f;
  unsigned int pk = 0;
  #pragma unroll
  for (int kk = 0; kk < 4; ++kk) {
    int q = (int)rintf(v[kk] / sunit);
    q = q > 127 ? 127 : (q < -127 ? -127 : q);
    pk |= ((unsigned int)(q & 255)) << (8 * kk);
  }
  size_t base = ((((size_t)(d * 16 + (jj >> 6)) * 4 + ((jj >> 4) & 3)) * 4 + (lane >> 4)) * 64
                 + ((((lane >> 2) & 3) << 4) | (jj & 15))) * 16 + (lane & 3) * 4;
  *(unsigned int*)&wpk[base] = pk;
  if (lane == 0) sw[j] = sunit / 127.f;
}

// ---------------- fused gather + input projection GEMM for one chunk ----------------
// M-row m = (d*T + tl)*256 + R (R = seq*128+b); A gathered from embbf via token ids.
// ginc layout: [(d*T+tl)*256 + R][j 0..1023] u16, fully-coalesced epilogue via LDS stage.
__global__ void __launch_bounds__(256, 2)
gemm_chunk_kernel(const int* __restrict__ x1, const int* __restrict__ x2,
                  const u16* __restrict__ embbf, const u16* __restrict__ wih_bf,
                  const float* __restrict__ bias, u16* __restrict__ ginc,
                  int t0, int T, int logT)
{
  __shared__ __align__(16) u16 smem[16384];     // As[8192] | Bs[8192]; epilogue: C[128][128]
  u16* As = smem;
  u16* Bs = smem + 8192;

  int m0 = blockIdx.x * 128;
  int d  = m0 >> (8 + logT);
  int tl = (m0 >> 8) & (T - 1);
  int R0 = m0 & 255;                 // 0 or 128 -> seq uniform per block
  int n0 = blockIdx.y * 128;
  int lane = threadIdx.x & 63;
  int w = threadIdx.x >> 6;
  int wm = w >> 1, wn = w & 1;

  const int* x = (R0 >> 7) ? x2 : x1;
  int t = t0 + tl;
  int tpos = d ? (255 - t) : t;

  int ar  = lane >> 3;               // row within 8-row stripe
  int acb = (lane & 7) * 16;         // byte col (16B slot)
  int sw  = ar << 4;

  // token ids for this thread's 4 staging rows (reused across all 5 k-tiles)
  int toks[4];
  #pragma unroll
  for (int i = 0; i < 4; ++i) {
    int lrow = (i * 4 + w) * 8 + ar;
    toks[i] = x[((R0 + lrow) & 127) * 256 + tpos];
  }

  f32x4v acc[4][4] = {};
  const char* Bbase = (const char*)(wih_bf + (size_t)d * 1024 * EPAD);
  const char* Ebase = (const char*)embbf;

  for (int kt = 0; kt < 5; ++kt) {
    int k0b = kt * 128;
    #pragma unroll
    for (int i = 0; i < 4; ++i) {
      int lrow = (i * 4 + w) * 8 + ar;
      gload_lds16(Ebase + (size_t)toks[i] * 640 + k0b + (acb ^ sw),
                  (char*)As + (i * 4 + w) * 1024);
      gload_lds16(Bbase + (size_t)(n0 + lrow) * 640 + k0b + (acb ^ sw),
                  (char*)Bs + (i * 4 + w) * 1024);
    }
    __syncthreads();
    #pragma unroll
    for (int kc = 0; kc < 2; ++kc) {
      s16x8 a[4], b[4];
      int cb = kc * 64 + (lane >> 4) * 16;
      #pragma unroll
      for (int mf = 0; mf < 4; ++mf) {
        int rr = wm * 64 + mf * 16 + (lane & 15);
        a[mf] = *(const s16x8*)((const char*)As + rr * 128 + (cb ^ ((rr & 7) << 4)));
      }
      #pragma unroll
      for (int nf = 0; nf < 4; ++nf) {
        int rr = wn * 64 + nf * 16 + (lane & 15);
        b[nf] = *(const s16x8*)((const char*)Bs + rr * 128 + (cb ^ ((rr & 7) << 4)));
      }
      #pragma unroll
      for (int mf = 0; mf < 4; ++mf)
        #pragma unroll
        for (int nf = 0; nf < 4; ++nf)
          acc[mf][nf] = __builtin_amdgcn_mfma_f32_16x16x32_bf16(a[mf], b[nf], acc[mf][nf], 0, 0, 0);
    }
    __syncthreads();
  }

  float bv[4];
  #pragma unroll
  for (int nf = 0; nf < 4; ++nf)
    bv[nf] = bias[d * 1024 + n0 + wn * 64 + nf * 16 + (lane & 15)];

  // stage C tile (bf16) into LDS, then fully-coalesced 256B-run stores
  #pragma unroll
  for (int mf = 0; mf < 4; ++mf)
    #pragma unroll
    for (int nf = 0; nf < 4; ++nf) {
      int col = wn * 64 + nf * 16 + (lane & 15);
      #pragma unroll
      for (int i = 0; i < 4; ++i) {
        int row = wm * 64 + mf * 16 + (lane >> 4) * 4 + i;
        smem[row * 128 + col] = f2bf(acc[mf][nf][i] + bv[nf]);
      }
    }
  __syncthreads();
  {
    size_t rowbase = ((size_t)(d * T + tl) * 256 + R0);
    int tid = threadIdx.x;
    #pragma unroll
    for (int it = 0; it < 8; ++it) {
      int chunk = it * 256 + tid;      // 0..2047 b128 chunks
      int row = chunk >> 4;
      int c16 = chunk & 15;
      *(s16x8*)(ginc + (rowbase + row) * 1024 + n0 + c16 * 8) =
          *(const s16x8*)(smem + row * 128 + c16 * 8);
    }
  }
}

// ---------------- recurrent bi-LSTM: 128 blocks = 2 dirs x 64 tiles of 4 rows ----------------
// Whh i8 register-resident; masked A-reads (only 4 real rows); lgkm-only barriers.
__global__ void __launch_bounds__(1024)
lstm_chunk_kernel(const u16* __restrict__ ginc, const i32x4* __restrict__ wpk,
                  const float* __restrict__ sw, char* hsave,
                  float* cstate, float* vaccst, float* vout,
                  const int* len1, const int* len2, int t0, int T)
{
  __shared__ __align__(16) char h_lds[4 * 288];   // i8 [4 rows][256 k] + 32B pad (bank stagger)
  __shared__ float g_lds[4 * 1028];               // f32 [4 rt][1024 j] + 4 pad

  const int bid = blockIdx.x;
  const int d = bid >> 6, bt = bid & 63;
  const int tid = threadIdx.x;
  const int lane = tid & 63, w = tid >> 6;        // wave 0..15

  // Whh i8 fragments -> registers; per-column scales
  i32x4 bfr[4][4];
  #pragma unroll
  for (int nf = 0; nf < 4; ++nf)
    #pragma unroll
    for (int kc = 0; kc < 4; ++kc)
      bfr[nf][kc] = wpk[(((size_t)(d * 16 + w) * 4 + nf) * 4 + kc) * 64 + lane];
  float swl[4];
  #pragma unroll
  for (int nf = 0; nf < 4; ++nf)
    swl[nf] = sw[d * 1024 + w * 64 + nf * 16 + (lane & 15)];

  const int rt = tid >> 8;           // 0..3
  const int u  = tid & 255;
  const int R  = bt * 4 + rt;
  const size_t sidx = ((size_t)d * 256 + R) * 256 + u;

  h_lds[rt * 288 + u] = (t0 > 0) ? hsave[sidx] : (char)0;

  int lm = ((R >> 7) ? len2 : len1)[R & 127] - 1;
  float c = 0.f, va = 0.f;
  if (t0 > 0) { c = cstate[sidx]; va = vaccst[sidx]; }

  const size_t step = (size_t)256 * 1024;          // u16 per timestep slab
  const u16* gp = ginc + ((size_t)d * T * 256 + R) * 1024 + u;
  u16 gv0 = gp[0], gv1 = gp[256], gv2 = gp[512], gv3 = gp[768];
  __syncthreads();

  const bool final_chunk = (t0 + T == 256);
  const int arow = lane & 15;

  for (int tl = 0; tl < T; ++tl) {
    // prefetch next step's gates (flies across both lgkm-only barriers)
    const u16* gpn = (tl + 1 < T) ? gp + step : gp;
    u16 n0v = gpn[0], n1v = gpn[256], n2v = gpn[512], n3v = gpn[768];

    // ---- MFMA phase: only lanes mapping to real A-rows read LDS ----
    i32x4 a0 = {0,0,0,0}, a1 = a0, a2 = a0, a3 = a0;
    if (arow < 4) {
      const char* hb = &h_lds[arow * 288 + (lane >> 4) * 16];
      a0 = *(const i32x4*)(hb);
      a1 = *(const i32x4*)(hb + 64);
      a2 = *(const i32x4*)(hb + 128);
      a3 = *(const i32x4*)(hb + 192);
    }
    #pragma unroll
    for (int nf = 0; nf < 4; ++nf) {
      i32x4 acc = {0, 0, 0, 0};
      acc = __builtin_amdgcn_mfma_i32_16x16x64_i8(a0, bfr[nf][0], acc, 0, 0, 0);
      acc = __builtin_amdgcn_mfma_i32_16x16x64_i8(a1, bfr[nf][1], acc, 0, 0, 0);
      acc = __builtin_amdgcn_mfma_i32_16x16x64_i8(a2, bfr[nf][2], acc, 0, 0, 0);
      acc = __builtin_amdgcn_mfma_i32_16x16x64_i8(a3, bfr[nf][3], acc, 0, 0, 0);
      if (lane < 16) {
        #pragma unroll
        for (int i = 0; i < 4; ++i)
          g_lds[i * 1028 + w * 64 + nf * 16 + lane] = (float)acc[i] * swl[nf];
      }
    }
    lds_barrier();

    // ---- gate phase: 1 cell (rt,u) per thread ----
    float si = g_lds[rt * 1028 +       u] + bf2f(gv0);
    float sf = g_lds[rt * 1028 + 256 + u] + bf2f(gv1);
    float sg = g_lds[rt * 1028 + 512 + u] + bf2f(gv2);
    float so = g_lds[rt * 1028 + 768 + u] + bf2f(gv3);
    float I = __builtin_amdgcn_rcpf(1.f + __expf(-si));
    float F = __builtin_amdgcn_rcpf(1.f + __expf(-sf));
    float sgc = fminf(fmaxf(sg, -15.f), 15.f);
    float G = 1.f - 2.f * __builtin_amdgcn_rcpf(__expf(2.f * sgc) + 1.f);
    float O = __builtin_amdgcn_rcpf(1.f + __expf(-so));
    float cn = F * c + I * G;
    c = cn;
    float cc2 = fminf(fmaxf(cn, -15.f), 15.f);
    float hn = O * (1.f - 2.f * __builtin_amdgcn_rcpf(__expf(2.f * cc2) + 1.f));
    int tmap = d ? (255 - (t0 + tl)) : (t0 + tl);
    if (tmap < lm) va += hn;
    int q = (int)rintf(fminf(fmaxf(hn, -0.9999f), 0.9999f) * 127.f);
    h_lds[rt * 288 + u] = (char)q;
    gv0 = n0v; gv1 = n1v; gv2 = n2v; gv3 = n3v;
    gp = gpn;
    lds_barrier();
  }

  cstate[sidx] = c;
  vaccst[sidx] = va;
  if (final_chunk) {
    int seq = R >> 7, bb = R & 127;
    vout[((size_t)seq * 128 + bb) * 512 + d * 256 + u] = va / (float)lm;
  } else {
    hsave[sidx] = h_lds[rt * 288 + u];
  }
}

// ---------------- MLP head ----------------
__global__ void mlp_kernel(const float* v, const float* W1, const float* b1,
                           const float* W2, const float* b2, const float* Wo, const float* bo,
                           float* out)
{
  __shared__ float vec[512];
  __shared__ float a1[512];
  __shared__ float red[4];
  int b = blockIdx.x;
  int tid = threadIdx.x;   // 256
  for (int i = tid; i < 512; i += 256)
    vec[i] = fabsf(v[(size_t)b * 512 + i] - v[(size_t)(128 + b) * 512 + i]);
  __syncthreads();
  for (int j = tid; j < 512; j += 256) {
    float s = b1[j];
    const float* wr = W1 + (size_t)j * 512;
    for (int k = 0; k < 512; ++k) s += vec[k] * wr[k];
    a1[j] = fmaxf(s, 0.f);
  }
  __syncthreads();
  float s = b2[tid];
  {
    const float* wr = W2 + (size_t)tid * 512;
    for (int k = 0; k < 512; ++k) s += a1[k] * wr[k];
  }
  float p = fmaxf(s, 0.f) * Wo[tid];
  for (int off = 32; off > 0; off >>= 1) p += __shfl_down(p, off);
  if ((tid & 63) == 0) red[tid >> 6] = p;
  __syncthreads();
  if (tid == 0) {
    float logit = red[0] + red[1] + red[2] + red[3] + bo[0];
    out[b] = logit;
    out[128 + b] = 1.f / (1.f + __expf(-logit));
  }
}

extern "C" void kernel_launch(void* const* d_in, const int* in_sizes, int n_in,
                              void* d_out, int out_size, void* d_ws, size_t ws_size,
                              hipStream_t stream)
{
  const int*   x1    = (const int*)d_in[0];
  const int*   x2    = (const int*)d_in[1];
  const int*   len1  = (const int*)d_in[2];
  const int*   len2  = (const int*)d_in[3];
  const float* emb   = (const float*)d_in[4];
  const float* wih_f = (const float*)d_in[5];
  const float* whh_f = (const float*)d_in[6];
  const float* bih_f = (const float*)d_in[7];
  const float* bhh_f = (const float*)d_in[8];
  const float* wih_b = (const float*)d_in[9];
  const float* whh_b = (const float*)d_in[10];
  const float* bih_b = (const float*)d_in[11];
  const float* bhh_b = (const float*)d_in[12];
  const float* W1    = (const float*)d_in[13];
  const float* b1    = (const float*)d_in[14];
  const float* W2    = (const float*)d_in[15];
  const float* b2    = (const float*)d_in[16];
  const float* Wo    = (const float*)d_in[17];
  const float* bo    = (const float*)d_in[18];

  char* p = (char*)d_ws;
  u16*   wih_bf = (u16*)p;          p += SZ_WIH;
  char*  wpk    = (char*)p;         p += SZ_WPK;
  float* swp    = (float*)p;        p += SZ_SW;
  float* bias   = (float*)p;        p += SZ_BIAS;
  char*  hsave  = (char*)p;         p += SZ_HSV;
  float* cst    = (float*)p;        p += SZ_CST;
  float* vac    = (float*)p;        p += SZ_VAC;
  float* vout   = (float*)p;        p += SZ_VOUT;
  u16*   embbf  = (u16*)p;          p += SZ_EMB;

  int T = 256;
  while (T > 1 && FIXED_B + (size_t)T * PER_T > ws_size) T >>= 1;
  int logT = __builtin_ctz((unsigned)T);
  u16* ginc = (u16*)p;              // [(d*T+tl)*256 + R][1024 j] u16

  {
    int total = 2 * 1024 * EPAD + 2 * 1024;
    prep_kernel<<<(total + 255) / 256, 256, 0, stream>>>(
        wih_f, bih_f, bhh_f, wih_b, bih_b, bhh_b, wih_bf, bias);
  }
  whhq_kernel<<<2048, 64, 0, stream>>>(whh_f, whh_b, wpk, swp);
  embconv_kernel<<<VOCAB, EPAD, 0, stream>>>(emb, embbf);

  int nch = 256 / T;
  for (int ch = 0; ch < nch; ++ch) {
    int tt0 = ch * T;
    gemm_chunk_kernel<<<dim3(4 * T, 8), 256, 0, stream>>>(x1, x2, embbf, wih_bf, bias,
                                                          ginc, tt0, T, logT);
    lstm_chunk_kernel<<<128, 1024, 0, stream>>>(ginc, (const i32x4*)wpk, swp, hsave,
                                                cst, vac, vout, len1, len2, tt0, T);
  }

  mlp_kernel<<<128, 256, 0, stream>>>(vout, W1, b1, W2, b2, Wo, bo, (float*)d_out);
}

// Round 7
// 563.560 us; speedup vs baseline: 20.6039x; 1.0061x over previous
//
#include <hip/hip_runtime.h>
#include <hip/hip_bf16.h>
#include <math.h>

typedef unsigned short u16;
typedef short s16x8 __attribute__((ext_vector_type(8)));
typedef float f32x4v __attribute__((ext_vector_type(4)));
typedef int i32x4 __attribute__((ext_vector_type(4)));
typedef unsigned short u16x4 __attribute__((ext_vector_type(4)));

#define EDIM 300
#define EPAD 320
#define VOCAB 50000

// ---- fixed workspace layout (bytes) ----
static constexpr size_t SZ_WIH  = (size_t)2 * 1024 * EPAD * 2;   // bf16 [2][1024 pack][320]
static constexpr size_t SZ_WPK  = (size_t)2 * 1024 * 256;        // i8 packed Whh frags
static constexpr size_t SZ_SW   = (size_t)2 * 1024 * 4;          // f32 per-row scale (pack order)
static constexpr size_t SZ_BIAS = (size_t)2 * 1024 * 4;          // f32 (pack order)
static constexpr size_t SZ_HSV  = (size_t)2 * 256 * 256;         // i8 h chunk-boundary save
static constexpr size_t SZ_CST  = (size_t)2 * 256 * 256 * 4;     // f32 c-state
static constexpr size_t SZ_VAC  = (size_t)2 * 256 * 256 * 4;     // f32 vacc-state
static constexpr size_t SZ_VOUT = (size_t)2 * 128 * 512 * 4;     // f32 [2][128][512]
static constexpr size_t SZ_EMB  = (size_t)VOCAB * EPAD * 2;      // bf16 emb table padded (32 MB)
static constexpr size_t FIXED_B = SZ_WIH + SZ_WPK + SZ_SW + SZ_BIAS + SZ_HSV + SZ_CST + SZ_VAC + SZ_VOUT + SZ_EMB;
static constexpr size_t PER_T   = (size_t)512 * 1024 * 2;        // ginc per step (1 MB)

// pack permutation: pack p = w*128 + q*16 + ul  (w=wave 0..7, q=uh*4+gate, ul 0..15)
//   -> logical Whh/Wih row jlog = gate*256 + w*32 + uh*16 + ul
// sigma (ginc column) s = w*128 + uh*64 + ul*4 + gate  (gates contiguous per cell)

__device__ __forceinline__ float bf2f(u16 u) {
  union { float f; unsigned int i; } v; v.i = ((unsigned int)u) << 16; return v.f;
}
__device__ __forceinline__ u16 f2bf(float f) {
  union { float f; unsigned int i; } v; v.f = f;
  unsigned int r = v.i + 0x7fffu + ((v.i >> 16) & 1u);   // RNE (finite inputs)
  return (u16)(r >> 16);
}
__device__ __forceinline__ void gload_lds16(const void* g, void* l) {
  __builtin_amdgcn_global_load_lds((const __attribute__((address_space(1))) void*)g,
                                   (__attribute__((address_space(3))) void*)l, 16, 0, 0);
}
// order LDS ops across waves WITHOUT draining vmcnt
__device__ __forceinline__ void lds_barrier() {
  asm volatile("s_waitcnt lgkmcnt(0)" ::: "memory");
  __builtin_amdgcn_s_barrier();
}

// ---------------- prep: Wih->bf16 padded (pack-row order), bias sum (pack order) ----------------
__global__ void prep_kernel(const float* wih_f, const float* bih_f, const float* bhh_f,
                            const float* wih_b, const float* bih_b, const float* bhh_b,
                            u16* wih_bf, float* bias)
{
  int tid = blockIdx.x * blockDim.x + threadIdx.x;
  if (tid < 2 * 1024 * EPAD) {
    int d = tid / (1024 * EPAD); int rr = tid % (1024 * EPAD);
    int p = rr / EPAD; int k = rr % EPAD;
    int w = p >> 7, q = (p >> 4) & 7, ul = p & 15;
    int jlog = (q & 3) * 256 + w * 32 + (q >> 2) * 16 + ul;
    const float* wsrc = d ? wih_b : wih_f;
    wih_bf[tid] = (k < EDIM) ? f2bf(wsrc[(size_t)jlog * EDIM + k]) : (u16)0;
  }
  int t2 = tid - 2 * 1024 * EPAD;
  if (t2 >= 0 && t2 < 2 * 1024) {
    int d = t2 >> 10; int p = t2 & 1023;
    int w = p >> 7, q = (p >> 4) & 7, ul = p & 15;
    int jlog = (q & 3) * 256 + w * 32 + (q >> 2) * 16 + ul;
    bias[t2] = d ? (bih_b[jlog] + bhh_b[jlog]) : (bih_f[jlog] + bhh_f[jlog]);
  }
}

// ---------------- emb -> bf16, K padded 300->320 (one-time) ----------------
__global__ void embconv_kernel(const float* emb, u16* embbf)
{
  int r = blockIdx.x;
  int k = threadIdx.x;     // 320
  embbf[(size_t)r * EPAD + k] = (k < EDIM) ? f2bf(emb[(size_t)r * EDIM + k]) : (u16)0;
}

// ---------------- Whh -> i8 quant + MFMA-fragment pack (8-wave pack order) ----------------
__global__ void whhq_kernel(const float* whh_f, const float* whh_b, char* wpk, float* sw)
{
  int jp = blockIdx.x;             // 0..2047 = d*1024 + pack p
  int t = threadIdx.x;             // 64
  int d = jp >> 10, p = jp & 1023;
  int w = p >> 7, q = (p >> 4) & 7, ul = p & 15;
  int jlog = (q & 3) * 256 + w * 32 + (q >> 2) * 16 + ul;
  const float* src = (d ? whh_b : whh_f) + (size_t)jlog * 256;
  float v[4]; float m = 0.f;
  #pragma unroll
  for (int kk = 0; kk < 4; ++kk) { v[kk] = src[t * 4 + kk]; m = fmaxf(m, fabsf(v[kk])); }
  #pragma unroll
  for (int off = 32; off > 0; off >>= 1) m = fmaxf(m, __shfl_xor(m, off));
  float sunit = m / 127.f;
  if (sunit < 1e-30f) sunit = 1e-30f;
  unsigned int pk = 0;
  #pragma unroll
  for (int kk = 0; kk < 4; ++kk) {
    int qv = (int)rintf(v[kk] / sunit);
    qv = qv > 127 ? 127 : (qv < -127 ? -127 : qv);
    pk |= ((unsigned int)(qv & 255)) << (8 * kk);
  }
  // frag entry (d,w,q,kc,lane=kg*16+ul): bytes = Wq[jlog][kc*64+kg*16 .. +16)
  size_t base = ((((size_t)(d * 8 + w) * 8 + q) * 4 + (t >> 4)) * 64
                 + (((t >> 2) & 3) * 16 + ul)) * 16 + (t & 3) * 4;
  *(unsigned int*)&wpk[base] = pk;
  if (t == 0) sw[jp] = sunit / 127.f;
}

// ---------------- fused gather + input projection GEMM for one chunk ----------------
// M-row m = (d*T + tl)*256 + R; B rows = pack order; epilogue stores sigma-permuted cols.
__global__ void __launch_bounds__(256, 2)
gemm_chunk_kernel(const int* __restrict__ x1, const int* __restrict__ x2,
                  const u16* __restrict__ embbf, const u16* __restrict__ wih_bf,
                  const float* __restrict__ bias, u16* __restrict__ ginc,
                  int t0, int T, int logT)
{
  __shared__ __align__(16) u16 smem[16384];     // As[8192] | Bs[8192]; epilogue: C[128][128]
  u16* As = smem;
  u16* Bs = smem + 8192;

  int m0 = blockIdx.x * 128;
  int d  = m0 >> (8 + logT);
  int tl = (m0 >> 8) & (T - 1);
  int R0 = m0 & 255;                 // 0 or 128
  int n0 = blockIdx.y * 128;         // = wave-slice w*128 of pack space
  int lane = threadIdx.x & 63;
  int w = threadIdx.x >> 6;
  int wm = w >> 1, wn = w & 1;

  const int* x = (R0 >> 7) ? x2 : x1;
  int t = t0 + tl;
  int tpos = d ? (255 - t) : t;

  int ar  = lane >> 3;
  int acb = (lane & 7) * 16;
  int sw  = ar << 4;

  int toks[4];
  #pragma unroll
  for (int i = 0; i < 4; ++i) {
    int lrow = (i * 4 + w) * 8 + ar;
    toks[i] = x[((R0 + lrow) & 127) * 256 + tpos];
  }

  f32x4v acc[4][4] = {};
  const char* Bbase = (const char*)(wih_bf + (size_t)d * 1024 * EPAD);
  const char* Ebase = (const char*)embbf;

  for (int kt = 0; kt < 5; ++kt) {
    int k0b = kt * 128;
    #pragma unroll
    for (int i = 0; i < 4; ++i) {
      int lrow = (i * 4 + w) * 8 + ar;
      gload_lds16(Ebase + (size_t)toks[i] * 640 + k0b + (acb ^ sw),
                  (char*)As + (i * 4 + w) * 1024);
      gload_lds16(Bbase + (size_t)(n0 + lrow) * 640 + k0b + (acb ^ sw),
                  (char*)Bs + (i * 4 + w) * 1024);
    }
    __syncthreads();
    #pragma unroll
    for (int kc = 0; kc < 2; ++kc) {
      s16x8 a[4], b[4];
      int cb = kc * 64 + (lane >> 4) * 16;
      #pragma unroll
      for (int mf = 0; mf < 4; ++mf) {
        int rr = wm * 64 + mf * 16 + (lane & 15);
        a[mf] = *(const s16x8*)((const char*)As + rr * 128 + (cb ^ ((rr & 7) << 4)));
      }
      #pragma unroll
      for (int nf = 0; nf < 4; ++nf) {
        int rr = wn * 64 + nf * 16 + (lane & 15);
        b[nf] = *(const s16x8*)((const char*)Bs + rr * 128 + (cb ^ ((rr & 7) << 4)));
      }
      #pragma unroll
      for (int mf = 0; mf < 4; ++mf)
        #pragma unroll
        for (int nf = 0; nf < 4; ++nf)
          acc[mf][nf] = __builtin_amdgcn_mfma_f32_16x16x32_bf16(a[mf], b[nf], acc[mf][nf], 0, 0, 0);
    }
    __syncthreads();
  }

  float bv[4];
  #pragma unroll
  for (int nf = 0; nf < 4; ++nf)
    bv[nf] = bias[d * 1024 + n0 + wn * 64 + nf * 16 + (lane & 15)];

  // stage C (bf16, pack cols) into LDS
  #pragma unroll
  for (int mf = 0; mf < 4; ++mf)
    #pragma unroll
    for (int nf = 0; nf < 4; ++nf) {
      int col = wn * 64 + nf * 16 + (lane & 15);
      #pragma unroll
      for (int i = 0; i < 4; ++i) {
        int row = wm * 64 + mf * 16 + (lane >> 4) * 4 + i;
        smem[row * 128 + col] = f2bf(acc[mf][nf][i] + bv[nf]);
      }
    }
  __syncthreads();
  // store with sigma col permutation: s = uh*64 + ul*4 + gate  <-  pack cl = (uh*4+gate)*16 + ul
  {
    size_t rowbase = ((size_t)(d * T + tl) * 256 + R0);
    int tid = threadIdx.x;
    #pragma unroll
    for (int it = 0; it < 8; ++it) {
      int chunk = it * 256 + tid;      // 2048 chunks of 8 u16
      int row = chunk >> 4;
      int s0 = (chunk & 15) * 8;
      s16x8 v;
      #pragma unroll
      for (int jj = 0; jj < 8; ++jj) {
        int s = s0 + jj;
        int gate = s & 3, ul = (s >> 2) & 15, uh = s >> 6;
        v[jj] = (short)smem[row * 128 + (uh * 4 + gate) * 16 + ul];
      }
      *(s16x8*)(ginc + (rowbase + row) * 1024 + n0 + s0) = v;
    }
  }
}

// ---------------- recurrent bi-LSTM: 256 blocks = 2 dir x 128 two-row tiles ----------------
// 8 waves; wave w owns u in [w*32,(w+1)*32) x 4 gates (in-register gate math).
// ONE lgkm-only barrier per step; h double-buffered in LDS.
__global__ void __launch_bounds__(512)
lstm_chunk_kernel(const u16* __restrict__ ginc, const i32x4* __restrict__ wpk,
                  const float* __restrict__ sw, char* hsave,
                  float* cstate, float* vaccst, float* vout,
                  const int* len1, const int* len2, int t0, int T)
{
  __shared__ __align__(16) char h_lds[2][2][288];   // [parity][row][256 k +pad]

  const int bid = blockIdx.x;
  const int d = bid >> 7, bt = bid & 127;
  const int tid = threadIdx.x;
  const int lane = tid & 63, w = tid >> 6;          // 8 waves
  const int cl = lane & 15;

  // Whh i8 fragments -> registers (AGPR-able); per-column scales (pack order)
  i32x4 bfr[8][4];
  #pragma unroll
  for (int q = 0; q < 8; ++q)
    #pragma unroll
    for (int kc = 0; kc < 4; ++kc)
      bfr[q][kc] = wpk[(((size_t)(d * 8 + w) * 8 + q) * 4 + kc) * 64 + lane];
  float swl[8];
  #pragma unroll
  for (int q = 0; q < 8; ++q)
    swl[q] = sw[d * 1024 + w * 128 + q * 16 + cl];

  const int R0 = bt * 2;
  {
    int r = tid >> 8, u = tid & 255;
    h_lds[0][r][u] = (t0 > 0) ? hsave[((size_t)d * 256 + R0 + r) * 256 + u] : (char)0;
  }

  int lm0 = ((R0 >> 7) ? len2 : len1)[R0 & 127] - 1;
  int lm1 = (((R0 + 1) >> 7) ? len2 : len1)[(R0 + 1) & 127] - 1;

  const bool gl = (lane < 16);
  float c[2][2] = {{0.f,0.f},{0.f,0.f}}, va[2][2] = {{0.f,0.f},{0.f,0.f}};
  if (t0 > 0 && gl) {
    #pragma unroll
    for (int r = 0; r < 2; ++r)
      #pragma unroll
      for (int uh = 0; uh < 2; ++uh) {
        size_t sidx = ((size_t)d * 256 + R0 + r) * 256 + (w * 32 + uh * 16 + cl);
        c[r][uh] = cstate[sidx];
        va[r][uh] = vaccst[sidx];
      }
  }

  const size_t GSTEP = (size_t)256 * 1024;
  const u16* gbase = ginc + ((size_t)d * T * 256 + R0) * 1024;
  u16x4 gv[2][2];
  if (gl) {
    #pragma unroll
    for (int r = 0; r < 2; ++r)
      #pragma unroll
      for (int uh = 0; uh < 2; ++uh)
        gv[r][uh] = *(const u16x4*)(gbase + (size_t)r * 1024 + w * 128 + uh * 64 + cl * 4);
  }
  __syncthreads();

  const bool final_chunk = (t0 + T == 256);
  int par = 0;

  for (int tl = 0; tl < T; ++tl) {
    // prefetch next step's gates (stays in flight across the barrier)
    const u16* gnb = gbase + GSTEP * (size_t)((tl + 1 < T) ? tl + 1 : tl);
    u16x4 gvn[2][2];
    if (gl) {
      #pragma unroll
      for (int r = 0; r < 2; ++r)
        #pragma unroll
        for (int uh = 0; uh < 2; ++uh)
          gvn[r][uh] = *(const u16x4*)(gnb + (size_t)r * 1024 + w * 128 + uh * 64 + cl * 4);
    }

    // A-frags (rows 0,1 real; others zero)
    i32x4 a[4] = {{0,0,0,0},{0,0,0,0},{0,0,0,0},{0,0,0,0}};
    if (cl < 2) {
      #pragma unroll
      for (int kc = 0; kc < 4; ++kc)
        a[kc] = *(const i32x4*)&h_lds[par][cl][kc * 64 + (lane >> 4) * 16];
    }
    i32x4 acc[8];
    #pragma unroll
    for (int q = 0; q < 8; ++q) {
      i32x4 z = {0, 0, 0, 0};
      #pragma unroll
      for (int kc = 0; kc < 4; ++kc)
        z = __builtin_amdgcn_mfma_i32_16x16x64_i8(a[kc], bfr[q][kc], z, 0, 0, 0);
      acc[q] = z;
    }

    // in-register gate math on lanes 0..15 (cells: 2 rows x 2 uh)
    if (gl) {
      int tmap = d ? (255 - (t0 + tl)) : (t0 + tl);
      #pragma unroll
      for (int r = 0; r < 2; ++r) {
        int lm = r ? lm1 : lm0;
        #pragma unroll
        for (int uh = 0; uh < 2; ++uh) {
          float s0 = (float)acc[uh * 4 + 0][r] * swl[uh * 4 + 0] + bf2f(gv[r][uh][0]);
          float s1 = (float)acc[uh * 4 + 1][r] * swl[uh * 4 + 1] + bf2f(gv[r][uh][1]);
          float s2 = (float)acc[uh * 4 + 2][r] * swl[uh * 4 + 2] + bf2f(gv[r][uh][2]);
          float s3 = (float)acc[uh * 4 + 3][r] * swl[uh * 4 + 3] + bf2f(gv[r][uh][3]);
          float I = __builtin_amdgcn_rcpf(1.f + __expf(-s0));
          float F = __builtin_amdgcn_rcpf(1.f + __expf(-s1));
          float G = 1.f - 2.f * __builtin_amdgcn_rcpf(__expf(2.f * s2) + 1.f);
          float O = __builtin_amdgcn_rcpf(1.f + __expf(-s3));
          float cn = F * c[r][uh] + I * G;
          c[r][uh] = cn;
          float hn = O * (1.f - 2.f * __builtin_amdgcn_rcpf(__expf(2.f * cn) + 1.f));
          if (tmap < lm) va[r][uh] += hn;
          h_lds[par ^ 1][r][w * 32 + uh * 16 + cl] = (char)(int)rintf(hn * 127.f);
        }
      }
    }
    lds_barrier();
    #pragma unroll
    for (int r = 0; r < 2; ++r)
      #pragma unroll
      for (int uh = 0; uh < 2; ++uh)
        gv[r][uh] = gvn[r][uh];
    par ^= 1;
  }

  if (gl) {
    #pragma unroll
    for (int r = 0; r < 2; ++r) {
      int lm = r ? lm1 : lm0;
      #pragma unroll
      for (int uh = 0; uh < 2; ++uh) {
        int u = w * 32 + uh * 16 + cl;
        size_t sidx = ((size_t)d * 256 + R0 + r) * 256 + u;
        cstate[sidx] = c[r][uh];
        vaccst[sidx] = va[r][uh];
        if (final_chunk) {
          int RR = R0 + r;
          vout[((size_t)(RR >> 7) * 128 + (RR & 127)) * 512 + d * 256 + u] = va[r][uh] / (float)lm;
        }
      }
    }
  }
  if (!final_chunk) {
    int r = tid >> 8, u = tid & 255;
    hsave[((size_t)d * 256 + R0 + r) * 256 + u] = h_lds[par][r][u];
  }
}

// ---------------- MLP head ----------------
__global__ void mlp_kernel(const float* v, const float* W1, const float* b1,
                           const float* W2, const float* b2, const float* Wo, const float* bo,
                           float* out)
{
  __shared__ float vec[512];
  __shared__ float a1[512];
  __shared__ float red[4];
  int b = blockIdx.x;
  int tid = threadIdx.x;   // 256
  for (int i = tid; i < 512; i += 256)
    vec[i] = fabsf(v[(size_t)b * 512 + i] - v[(size_t)(128 + b) * 512 + i]);
  __syncthreads();
  for (int j = tid; j < 512; j += 256) {
    float s = b1[j];
    const float* wr = W1 + (size_t)j * 512;
    for (int k = 0; k < 512; ++k) s += vec[k] * wr[k];
    a1[j] = fmaxf(s, 0.f);
  }
  __syncthreads();
  float s = b2[tid];
  {
    const float* wr = W2 + (size_t)tid * 512;
    for (int k = 0; k < 512; ++k) s += a1[k] * wr[k];
  }
  float p = fmaxf(s, 0.f) * Wo[tid];
  for (int off = 32; off > 0; off >>= 1) p += __shfl_down(p, off);
  if ((tid & 63) == 0) red[tid >> 6] = p;
  __syncthreads();
  if (tid == 0) {
    float logit = red[0] + red[1] + red[2] + red[3] + bo[0];
    out[b] = logit;
    out[128 + b] = 1.f / (1.f + __expf(-logit));
  }
}

extern "C" void kernel_launch(void* const* d_in, const int* in_sizes, int n_in,
                              void* d_out, int out_size, void* d_ws, size_t ws_size,
                              hipStream_t stream)
{
  const int*   x1    = (const int*)d_in[0];
  const int*   x2    = (const int*)d_in[1];
  const int*   len1  = (const int*)d_in[2];
  const int*   len2  = (const int*)d_in[3];
  const float* emb   = (const float*)d_in[4];
  const float* wih_f = (const float*)d_in[5];
  const float* whh_f = (const float*)d_in[6];
  const float* bih_f = (const float*)d_in[7];
  const float* bhh_f = (const float*)d_in[8];
  const float* wih_b = (const float*)d_in[9];
  const float* whh_b = (const float*)d_in[10];
  const float* bih_b = (const float*)d_in[11];
  const float* bhh_b = (const float*)d_in[12];
  const float* W1    = (const float*)d_in[13];
  const float* b1    = (const float*)d_in[14];
  const float* W2    = (const float*)d_in[15];
  const float* b2    = (const float*)d_in[16];
  const float* Wo    = (const float*)d_in[17];
  const float* bo    = (const float*)d_in[18];

  char* p = (char*)d_ws;
  u16*   wih_bf = (u16*)p;          p += SZ_WIH;
  char*  wpk    = (char*)p;         p += SZ_WPK;
  float* swp    = (float*)p;        p += SZ_SW;
  float* bias   = (float*)p;        p += SZ_BIAS;
  char*  hsave  = (char*)p;         p += SZ_HSV;
  float* cst    = (float*)p;        p += SZ_CST;
  float* vac    = (float*)p;        p += SZ_VAC;
  float* vout   = (float*)p;        p += SZ_VOUT;
  u16*   embbf  = (u16*)p;          p += SZ_EMB;

  int T = 256;
  while (T > 1 && FIXED_B + (size_t)T * PER_T > ws_size) T >>= 1;
  int logT = __builtin_ctz((unsigned)T);
  u16* ginc = (u16*)p;              // [(d*T+tl)*256 + R][1024 sigma-cols] u16

  {
    int total = 2 * 1024 * EPAD + 2 * 1024;
    prep_kernel<<<(total + 255) / 256, 256, 0, stream>>>(
        wih_f, bih_f, bhh_f, wih_b, bih_b, bhh_b, wih_bf, bias);
  }
  whhq_kernel<<<2048, 64, 0, stream>>>(whh_f, whh_b, wpk, swp);
  embconv_kernel<<<VOCAB, EPAD, 0, stream>>>(emb, embbf);

  int nch = 256 / T;
  for (int ch = 0; ch < nch; ++ch) {
    int tt0 = ch * T;
    gemm_chunk_kernel<<<dim3(4 * T, 8), 256, 0, stream>>>(x1, x2, embbf, wih_bf, bias,
                                                          ginc, tt0, T, logT);
    lstm_chunk_kernel<<<256, 512, 0, stream>>>(ginc, (const i32x4*)wpk, swp, hsave,
                                               cst, vac, vout, len1, len2, tt0, T);
  }

  mlp_kernel<<<128, 256, 0, stream>>>(vout, W1, b1, W2, b2, Wo, bo, (float*)d_out);
}